// Round 2
// baseline (1791.885 us; speedup 1.0000x reference)
//
#include <hip/hip_runtime.h>

typedef unsigned short u16;
typedef __attribute__((ext_vector_type(8))) short bf16x8;
typedef __attribute__((ext_vector_type(4))) float f32x4;

static __device__ __forceinline__ float bf2f(u16 u) {
  union { unsigned int i; float f; } v; v.i = ((unsigned int)u) << 16; return v.f;
}
static __device__ __forceinline__ u16 f2bf(float f) {
  union { float f; unsigned int i; } v; v.f = f;
  unsigned int i = v.i;
  return (u16)((i + 0x7FFFu + ((i >> 16) & 1u)) >> 16);
}

// ---- convert f32 -> bf16, vectorized ----
__global__ __launch_bounds__(256) void cvt_f32_bf16(const float* __restrict__ src,
                                                    u16* __restrict__ dst, int n4)
{
  int i = blockIdx.x * 256 + threadIdx.x;
  if (i >= n4) return;
  float4 v = ((const float4*)src)[i];
  ushort4 r;
  r.x = f2bf(v.x); r.y = f2bf(v.y); r.z = f2bf(v.z); r.w = f2bf(v.w);
  ((ushort4*)dst)[i] = r;
}

// ---- GEMM: acc_f32( X[M,K]bf16 @ Wt[N,K]^T bf16 ); store bf16 or f32 ----
__global__ __launch_bounds__(256) void gemm_bf16(
    const u16* __restrict__ X, const u16* __restrict__ Wt,
    u16* __restrict__ out16, float* __restrict__ out32,
    const float* __restrict__ bias, int M, int N, int K)
{
  const int NW = 4;
  int wave = threadIdx.x >> 6, lane = threadIdx.x & 63;
  int quad = lane >> 4, l16 = lane & 15;
  int mbase = blockIdx.x * 64 + wave * 16;
  if (mbase >= M) return;                 // M % 16 == 0 for all our shapes
  int nbase = blockIdx.y * 64;
  const u16* xptr = X + (size_t)(mbase + l16) * K + quad * 8;
  const u16* wptr = Wt + (size_t)(nbase + l16) * K + quad * 8;
  f32x4 acc[NW];
#pragma unroll
  for (int j = 0; j < NW; ++j) acc[j] = (f32x4){0.f, 0.f, 0.f, 0.f};
  for (int k = 0; k < K; k += 32) {
    bf16x8 a = *(const bf16x8*)(xptr + k);
#pragma unroll
    for (int j = 0; j < NW; ++j) {
      bf16x8 b = *(const bf16x8*)(wptr + (size_t)j * 16 * K + k);
      acc[j] = __builtin_amdgcn_mfma_f32_16x16x32_bf16(a, b, acc[j], 0, 0, 0);
    }
  }
#pragma unroll
  for (int j = 0; j < NW; ++j) {
    int col = nbase + j * 16 + l16;
    float bv = bias ? bias[col] : 0.f;
#pragma unroll
    for (int r = 0; r < 4; ++r) {
      int row = mbase + quad * 4 + r;
      float v = acc[j][r] + bv;
      if (out32) out32[(size_t)row * N + col] = v;
      else       out16[(size_t)row * N + col] = f2bf(v);
    }
  }
}

// ---- transpose: dst[n*K + k] (bf16) = src[k*N + n] (f32) ----
__global__ __launch_bounds__(256) void transpose_k(const float* __restrict__ src,
                                                   u16* __restrict__ dst, int K, int N)
{
  int idx = blockIdx.x * 256 + threadIdx.x;
  if (idx >= K * N) return;
  int k = idx / N, n = idx - k * N;
  dst[(size_t)n * K + k] = f2bf(src[idx]);
}

// ---- wr[k][h] = sum_d W[k][h*64+d] * ar[h][d]  (f32) ----
__global__ __launch_bounds__(256) void build_wr(const float* __restrict__ W,
                                                const float* __restrict__ ar,
                                                float* __restrict__ wr, int K)
{
  int idx = blockIdx.x * 256 + threadIdx.x;
  if (idx >= K * 4) return;
  int k = idx >> 2, h = idx & 3;
  float s = 0.f;
  for (int d = 0; d < 64; ++d)
    s += W[(size_t)k * 256 + h * 64 + d] * ar[h * 64 + d];
  wr[idx] = s;
}

// ---- el/er from fs(bf16): el[n][h] = sum_d fs[n][h*64+d]*al[h][d] ----
__global__ __launch_bounds__(256) void elr_kernel(
    const u16* __restrict__ fs, const float* __restrict__ al, const float* __restrict__ ar,
    float* __restrict__ el, float* __restrict__ er, int N)
{
  int nid = blockIdx.x * 4 + (threadIdx.x >> 6);
  if (nid >= N) return;
  int lane = threadIdx.x & 63, h = lane >> 4;
  ushort4 f4 = *(const ushort4*)(fs + (size_t)nid * 256 + lane * 4);
  float f0 = bf2f(f4.x), f1 = bf2f(f4.y), f2 = bf2f(f4.z), f3 = bf2f(f4.w);
  {
    float4 a4 = *(const float4*)(al + lane * 4);
    float p = f0 * a4.x + f1 * a4.y + f2 * a4.z + f3 * a4.w;
    for (int off = 1; off < 16; off <<= 1) p += __shfl_xor(p, off);
    if ((lane & 15) == 0) el[nid * 4 + h] = p;
  }
  if (ar) {
    float4 a4 = *(const float4*)(ar + lane * 4);
    float p = f0 * a4.x + f1 * a4.y + f2 * a4.z + f3 * a4.w;
    for (int off = 1; off < 16; off <<= 1) p += __shfl_xor(p, off);
    if ((lane & 15) == 0) er[nid * 4 + h] = p;
  }
}

// ---- er[n][h] = sum_k X[n][k](bf16) * wr[k][h] ----
__global__ __launch_bounds__(256) void er_wr_kernel(
    const u16* __restrict__ X, const float* __restrict__ wr,
    float* __restrict__ er, int N, int K)
{
  int nid = blockIdx.x * 4 + (threadIdx.x >> 6);
  if (nid >= N) return;
  int lane = threadIdx.x & 63;
  float a0 = 0.f, a1 = 0.f, a2 = 0.f, a3 = 0.f;
  for (int k = lane; k < K; k += 64) {
    float xv = bf2f(X[(size_t)nid * K + k]);
    const float* w = wr + k * 4;
    a0 += xv * w[0]; a1 += xv * w[1]; a2 += xv * w[2]; a3 += xv * w[3];
  }
  for (int off = 1; off < 64; off <<= 1) {
    a0 += __shfl_xor(a0, off); a1 += __shfl_xor(a1, off);
    a2 += __shfl_xor(a2, off); a3 += __shfl_xor(a3, off);
  }
  if (lane == 0) {
    er[nid * 4 + 0] = a0; er[nid * 4 + 1] = a1;
    er[nid * 4 + 2] = a2; er[nid * 4 + 3] = a3;
  }
}

// ---- CSR build ----
__global__ __launch_bounds__(256) void zero_i32(int* p, int n) {
  int i = blockIdx.x * 256 + threadIdx.x;
  if (i < n) p[i] = 0;
}
__global__ __launch_bounds__(256) void hist_kernel(const int* __restrict__ dst, int E,
                                                   int* __restrict__ deg) {
  int i = blockIdx.x * 256 + threadIdx.x;
  if (i < E) atomicAdd(&deg[dst[i]], 1);
}
__global__ __launch_bounds__(256) void scanA(const int* __restrict__ deg,
                                             int* __restrict__ rowptr,
                                             int* __restrict__ bsums, int N) {
  __shared__ int sm[256];
  int t = threadIdx.x, i = blockIdx.x * 256 + t;
  int v = (i < N) ? deg[i] : 0;
  sm[t] = v; __syncthreads();
  for (int off = 1; off < 256; off <<= 1) {
    int add = (t >= off) ? sm[t - off] : 0;
    __syncthreads();
    sm[t] += add;
    __syncthreads();
  }
  if (i < N) rowptr[i] = sm[t] - v;     // exclusive within block
  if (t == 255) bsums[blockIdx.x] = sm[255];
}
__global__ __launch_bounds__(512) void scanB(int* bsums, int nb) {
  __shared__ int sm[512];
  int t = threadIdx.x;
  int v = (t < nb) ? bsums[t] : 0;
  sm[t] = v; __syncthreads();
  for (int off = 1; off < 512; off <<= 1) {
    int add = (t >= off) ? sm[t - off] : 0;
    __syncthreads();
    sm[t] += add;
    __syncthreads();
  }
  if (t < nb) bsums[t] = sm[t] - v;     // exclusive block offsets
}
__global__ __launch_bounds__(256) void scanC(int* __restrict__ rowptr,
                                             const int* __restrict__ bsums, int N, int E) {
  int i = blockIdx.x * 256 + threadIdx.x;
  if (i < N) rowptr[i] += bsums[blockIdx.x];
  if (blockIdx.x == 0 && threadIdx.x == 0) rowptr[N] = E;
}
__global__ __launch_bounds__(256) void copy_i32(int* __restrict__ d, const int* __restrict__ s, int n) {
  int i = blockIdx.x * 256 + threadIdx.x;
  if (i < n) d[i] = s[i];
}
__global__ __launch_bounds__(256) void fill_kernel(const int* __restrict__ dst, int E,
                                                   int* __restrict__ cursor,
                                                   int* __restrict__ eids) {
  int i = blockIdx.x * 256 + threadIdx.x;
  if (i < E) {
    int pos = atomicAdd(&cursor[dst[i]], 1);
    eids[pos] = i;
  }
}

// ---- per-dst-node softmax aggregation of one relation (wave = one node) ----
static __device__ __forceinline__ void softagg(
    int nid, int lane, int h,
    const int* __restrict__ rp, const int* __restrict__ eids, const int* __restrict__ src,
    const float* __restrict__ el, const float* __restrict__ er, const u16* __restrict__ fs,
    float& a0, float& a1, float& a2, float& a3)
{
  int s0 = rp[nid], s1 = rp[nid + 1];
  if (s1 <= s0) return;
  float ern = er[nid * 4 + h];
  float m = -1e30f;
  for (int i = s0 + (lane & 15); i < s1; i += 16) {
    int e = eids[i];
    float v = el[src[e] * 4 + h] + ern;
    v = v > 0.f ? v : 0.2f * v;
    m = fmaxf(m, v);
  }
  for (int off = 1; off < 16; off <<= 1) m = fmaxf(m, __shfl_xor(m, off));
  float s = 0.f;
  for (int i = s0 + (lane & 15); i < s1; i += 16) {
    int e = eids[i];
    float v = el[src[e] * 4 + h] + ern;
    v = v > 0.f ? v : 0.2f * v;
    s += __expf(v - m);
  }
  for (int off = 1; off < 16; off <<= 1) s += __shfl_xor(s, off);
  float inv = 1.f / s;
  for (int i = s0; i < s1; ++i) {
    int e = eids[i];
    int sid = src[e];
    float v = el[sid * 4 + h] + ern;
    v = v > 0.f ? v : 0.2f * v;
    float w = __expf(v - m) * inv;
    ushort4 f4 = *(const ushort4*)(fs + (size_t)sid * 256 + lane * 4);
    a0 += w * bf2f(f4.x); a1 += w * bf2f(f4.y);
    a2 += w * bf2f(f4.z); a3 += w * bf2f(f4.w);
  }
}

// ---- paper-dst aggregation: rel cites (paper src) + rel writes (author src) ----
__global__ __launch_bounds__(256) void agg_paper(
    const int* rp0, const int* eid0, const int* src0,
    const float* el0, const float* er0, const u16* fs0,
    const int* rp1, const int* eid1, const int* src1,
    const float* el1, const float* er1, const u16* fs1,
    const float* __restrict__ bias0, const float* __restrict__ bias1,
    u16* __restrict__ out, int Nd, int relu)
{
  int nid = blockIdx.x * 4 + (threadIdx.x >> 6);
  if (nid >= Nd) return;
  int lane = threadIdx.x & 63, h = lane >> 4;
  float a0 = 0.f, a1 = 0.f, a2 = 0.f, a3 = 0.f;
  softagg(nid, lane, h, rp0, eid0, src0, el0, er0, fs0, a0, a1, a2, a3);
  softagg(nid, lane, h, rp1, eid1, src1, el1, er1, fs1, a0, a1, a2, a3);
  int c = lane * 4;
  float o0 = a0 + bias0[c + 0] + bias1[c + 0];
  float o1 = a1 + bias0[c + 1] + bias1[c + 1];
  float o2 = a2 + bias0[c + 2] + bias1[c + 2];
  float o3 = a3 + bias0[c + 3] + bias1[c + 3];
  if (relu) {
    o0 = fmaxf(o0, 0.f); o1 = fmaxf(o1, 0.f);
    o2 = fmaxf(o2, 0.f); o3 = fmaxf(o3, 0.f);
  }
  ushort4 r;
  r.x = f2bf(o0); r.y = f2bf(o1); r.z = f2bf(o2); r.w = f2bf(o3);
  *(ushort4*)(out + (size_t)nid * 256 + c) = r;
}

// ---- author-dst aggregation: rel written (paper src) ----
__global__ __launch_bounds__(256) void agg_author(
    const int* rp0, const int* eid0, const int* src0,
    const float* el0, const float* er0, const u16* fs0,
    const float* __restrict__ bias0, u16* __restrict__ out, int Nd, int relu)
{
  int nid = blockIdx.x * 4 + (threadIdx.x >> 6);
  if (nid >= Nd) return;
  int lane = threadIdx.x & 63, h = lane >> 4;
  float a0 = 0.f, a1 = 0.f, a2 = 0.f, a3 = 0.f;
  softagg(nid, lane, h, rp0, eid0, src0, el0, er0, fs0, a0, a1, a2, a3);
  int c = lane * 4;
  float o0 = a0 + bias0[c + 0];
  float o1 = a1 + bias0[c + 1];
  float o2 = a2 + bias0[c + 2];
  float o3 = a3 + bias0[c + 3];
  if (relu) {
    o0 = fmaxf(o0, 0.f); o1 = fmaxf(o1, 0.f);
    o2 = fmaxf(o2, 0.f); o3 = fmaxf(o3, 0.f);
  }
  ushort4 r;
  r.x = f2bf(o0); r.y = f2bf(o1); r.z = f2bf(o2); r.w = f2bf(o3);
  *(ushort4*)(out + (size_t)nid * 256 + c) = r;
}

static inline int cdiv(int a, int b) { return (a + b - 1) / b; }

extern "C" void kernel_launch(void* const* d_in, const int* in_sizes, int n_in,
                              void* d_out, int out_size, void* d_ws, size_t ws_size,
                              hipStream_t stream)
{
  const float* xp   = (const float*)d_in[0];
  const float* xa   = (const float*)d_in[1];
  const float* W0   = (const float*)d_in[2];   // [3][128][256]
  const float* al0  = (const float*)d_in[3];   // [3][4][64]
  const float* ar0  = (const float*)d_in[4];
  const float* b0   = (const float*)d_in[5];   // [3][256]
  const float* W1   = (const float*)d_in[6];   // [3][256][256]
  const float* al1  = (const float*)d_in[7];
  const float* ar1  = (const float*)d_in[8];
  const float* b1   = (const float*)d_in[9];
  const float* linw = (const float*)d_in[10];  // [256][192]
  const float* linb = (const float*)d_in[11];  // [192]
  const int* srcC = (const int*)d_in[12];
  const int* dstC = (const int*)d_in[13];
  const int* srcW = (const int*)d_in[14];
  const int* dstW = (const int*)d_in[15];
  const int* srcR = (const int*)d_in[16];
  const int* dstR = (const int*)d_in[17];
  float* out = (float*)d_out;

  const int Np = in_sizes[0] / 128;
  const int Na = in_sizes[1] / 128;
  const int E  = in_sizes[12];

  // workspace carve-up
  char* base = (char*)d_ws;
  size_t off = 0;
  auto alloc = [&](size_t bytes) -> void* {
    void* r = base + off;
    off += (bytes + 255) & ~(size_t)255;
    return r;
  };
  u16* Wt0  = (u16*)alloc((size_t)3 * 256 * 128 * 2);   // [r][n=256][k=128] bf16
  u16* Wt1  = (u16*)alloc((size_t)3 * 256 * 256 * 2);   // [r][n=256][k=256] bf16
  u16* Wtl  = (u16*)alloc((size_t)192 * 256 * 2);       // [n=192][k=256] bf16
  float* wr01 = (float*)alloc(128 * 4 * 4);
  float* wr02 = (float*)alloc(128 * 4 * 4);
  float* wr11 = (float*)alloc(256 * 4 * 4);
  float* wr12 = (float*)alloc(256 * 4 * 4);
  u16* xpb  = (u16*)alloc((size_t)Np * 128 * 2);        // bf16 copies of inputs
  u16* xab  = (u16*)alloc((size_t)Na * 128 * 2);
  u16* fs0p = (u16*)alloc((size_t)Np * 256 * 2);        // bf16 feature bufs (reused L0/L1)
  u16* fs1a = (u16*)alloc((size_t)Na * 256 * 2);
  u16* fs2p = (u16*)alloc((size_t)Np * 256 * 2);
  u16* h1p  = (u16*)alloc((size_t)Np * 256 * 2);        // layer outputs bf16 (reused)
  u16* h1a  = (u16*)alloc((size_t)Na * 256 * 2);
  float* el0 = (float*)alloc((size_t)Np * 4 * 4);
  float* er0 = (float*)alloc((size_t)Np * 4 * 4);
  float* el1 = (float*)alloc((size_t)Na * 4 * 4);
  float* er1 = (float*)alloc((size_t)Np * 4 * 4);
  float* el2 = (float*)alloc((size_t)Np * 4 * 4);
  float* er2 = (float*)alloc((size_t)Na * 4 * 4);
  int* rpC  = (int*)alloc((size_t)(Np + 1) * 4);
  int* rpW  = (int*)alloc((size_t)(Np + 1) * 4);
  int* rpR  = (int*)alloc((size_t)(Na + 1) * 4);
  int* eidC = (int*)alloc((size_t)E * 4);
  int* eidW = (int*)alloc((size_t)E * 4);
  int* eidR = (int*)alloc((size_t)E * 4);
  int* deg    = (int*)alloc((size_t)Np * 4);
  int* cursor = (int*)alloc((size_t)Np * 4);
  int* bsums  = (int*)alloc(512 * 4);

  // ---- input conversion + weight prep ----
  cvt_f32_bf16<<<cdiv(Np * 32, 256), 256, 0, stream>>>(xp, xpb, Np * 32);
  cvt_f32_bf16<<<cdiv(Na * 32, 256), 256, 0, stream>>>(xa, xab, Na * 32);
  for (int r = 0; r < 3; ++r)
    transpose_k<<<cdiv(128 * 256, 256), 256, 0, stream>>>(W0 + (size_t)r * 32768,
                                                          Wt0 + (size_t)r * 32768, 128, 256);
  for (int r = 0; r < 3; ++r)
    transpose_k<<<cdiv(256 * 256, 256), 256, 0, stream>>>(W1 + (size_t)r * 65536,
                                                          Wt1 + (size_t)r * 65536, 256, 256);
  transpose_k<<<cdiv(256 * 192, 256), 256, 0, stream>>>(linw, Wtl, 256, 192);
  build_wr<<<cdiv(128 * 4, 256), 256, 0, stream>>>(W0 + 1 * 32768, ar0 + 256, wr01, 128);
  build_wr<<<cdiv(128 * 4, 256), 256, 0, stream>>>(W0 + 2 * 32768, ar0 + 512, wr02, 128);
  build_wr<<<cdiv(256 * 4, 256), 256, 0, stream>>>(W1 + 1 * 65536, ar1 + 256, wr11, 256);
  build_wr<<<cdiv(256 * 4, 256), 256, 0, stream>>>(W1 + 2 * 65536, ar1 + 512, wr12, 256);

  // ---- CSR build (shared by both layers) ----
  auto build_csr = [&](const int* dst, int Nd, int* rp, int* eids) {
    int nb = cdiv(Nd, 256);
    zero_i32<<<nb, 256, 0, stream>>>(deg, Nd);
    hist_kernel<<<cdiv(E, 256), 256, 0, stream>>>(dst, E, deg);
    scanA<<<nb, 256, 0, stream>>>(deg, rp, bsums, Nd);
    scanB<<<1, 512, 0, stream>>>(bsums, nb);
    scanC<<<nb, 256, 0, stream>>>(rp, bsums, Nd, E);
    copy_i32<<<nb, 256, 0, stream>>>(cursor, rp, Nd);
    fill_kernel<<<cdiv(E, 256), 256, 0, stream>>>(dst, E, cursor, eids);
  };
  build_csr(dstC, Np, rpC, eidC);
  build_csr(dstW, Np, rpW, eidW);
  build_csr(dstR, Na, rpR, eidR);

  dim3 blk(256);
  auto gemm = [&](const u16* X, const u16* Wt, u16* O16, float* O32,
                  const float* bias, int M, int N, int K) {
    dim3 grid(cdiv(M, 64), N / 64);
    gemm_bf16<<<grid, blk, 0, stream>>>(X, Wt, O16, O32, bias, M, N, K);
  };

  // ---- layer 0 ----
  gemm(xpb, Wt0,          fs0p, nullptr, nullptr, Np, 256, 128);
  gemm(xab, Wt0 + 32768,  fs1a, nullptr, nullptr, Na, 256, 128);
  gemm(xpb, Wt0 + 65536,  fs2p, nullptr, nullptr, Np, 256, 128);
  elr_kernel<<<cdiv(Np, 4), 256, 0, stream>>>(fs0p, al0,       ar0, el0, er0, Np);
  elr_kernel<<<cdiv(Na, 4), 256, 0, stream>>>(fs1a, al0 + 256, nullptr, el1, nullptr, Na);
  elr_kernel<<<cdiv(Np, 4), 256, 0, stream>>>(fs2p, al0 + 512, nullptr, el2, nullptr, Np);
  er_wr_kernel<<<cdiv(Np, 4), 256, 0, stream>>>(xpb, wr01, er1, Np, 128);
  er_wr_kernel<<<cdiv(Na, 4), 256, 0, stream>>>(xab, wr02, er2, Na, 128);
  agg_paper<<<cdiv(Np, 4), 256, 0, stream>>>(rpC, eidC, srcC, el0, er0, fs0p,
                                             rpW, eidW, srcW, el1, er1, fs1a,
                                             b0, b0 + 256, h1p, Np, 1);
  agg_author<<<cdiv(Na, 4), 256, 0, stream>>>(rpR, eidR, srcR, el2, er2, fs2p,
                                              b0 + 512, h1a, Na, 1);

  // ---- layer 1 ----
  gemm(h1p, Wt1,           fs0p, nullptr, nullptr, Np, 256, 256);
  gemm(h1a, Wt1 + 65536,   fs1a, nullptr, nullptr, Na, 256, 256);
  gemm(h1p, Wt1 + 131072,  fs2p, nullptr, nullptr, Np, 256, 256);
  elr_kernel<<<cdiv(Np, 4), 256, 0, stream>>>(fs0p, al1,       ar1, el0, er0, Np);
  elr_kernel<<<cdiv(Na, 4), 256, 0, stream>>>(fs1a, al1 + 256, nullptr, el1, nullptr, Na);
  elr_kernel<<<cdiv(Np, 4), 256, 0, stream>>>(fs2p, al1 + 512, nullptr, el2, nullptr, Np);
  er_wr_kernel<<<cdiv(Np, 4), 256, 0, stream>>>(h1p, wr11, er1, Np, 256);
  er_wr_kernel<<<cdiv(Na, 4), 256, 0, stream>>>(h1a, wr12, er2, Na, 256);
  agg_paper<<<cdiv(Np, 4), 256, 0, stream>>>(rpC, eidC, srcC, el0, er0, fs0p,
                                             rpW, eidW, srcW, el1, er1, fs1a,
                                             b1, b1 + 256, h1p, Np, 0);
  agg_author<<<cdiv(Na, 4), 256, 0, stream>>>(rpR, eidR, srcR, el2, er2, fs2p,
                                              b1 + 512, h1a, Na, 0);

  // ---- final linear ----
  gemm(h1p, Wtl, nullptr, out, linb, Np, 192, 256);
}

// Round 4
// 1393.895 us; speedup vs baseline: 1.2855x; 1.2855x over previous
//
#include <hip/hip_runtime.h>

typedef unsigned short u16;
typedef __attribute__((ext_vector_type(8))) short bf16x8;
typedef __attribute__((ext_vector_type(4))) float f32x4;

static __device__ __forceinline__ float bf2f(u16 u) {
  union { unsigned int i; float f; } v; v.i = ((unsigned int)u) << 16; return v.f;
}
static __device__ __forceinline__ u16 f2bf(float f) {
  union { float f; unsigned int i; } v; v.f = f;
  unsigned int i = v.i;
  return (u16)((i + 0x7FFFu + ((i >> 16) & 1u)) >> 16);
}

// ---- convert f32 -> bf16, vectorized ----
__global__ __launch_bounds__(256) void cvt_f32_bf16(const float* __restrict__ src,
                                                    u16* __restrict__ dst, int n4)
{
  int i = blockIdx.x * 256 + threadIdx.x;
  if (i >= n4) return;
  float4 v = ((const float4*)src)[i];
  ushort4 r;
  r.x = f2bf(v.x); r.y = f2bf(v.y); r.z = f2bf(v.z); r.w = f2bf(v.w);
  ((ushort4*)dst)[i] = r;
}

// ---- GEMM: full-N per block. out[M,N] = X[M,K]bf16 @ Wt[N,K]^T ----
// block 256 thr = 4 waves * 16 rows; each wave computes 16 x N. X read once.
template<int K, int NT>
__global__ __launch_bounds__(256) void gemm_bf16(
    const u16* __restrict__ X, const u16* __restrict__ Wt,
    u16* __restrict__ out16, float* __restrict__ out32,
    const float* __restrict__ bias, int M)
{
  const int N = NT * 16;
  int wave = threadIdx.x >> 6, lane = threadIdx.x & 63;
  int quad = lane >> 4, l16 = lane & 15;
  int mbase = blockIdx.x * 64 + wave * 16;
  if (mbase >= M) return;                 // M % 16 == 0 for all our shapes
  const u16* xptr = X + (size_t)(mbase + l16) * K + quad * 8;
  const u16* wptr = Wt + (size_t)l16 * K + quad * 8;
  f32x4 acc[NT];
#pragma unroll
  for (int j = 0; j < NT; ++j) acc[j] = (f32x4){0.f, 0.f, 0.f, 0.f};
  for (int k = 0; k < K; k += 32) {
    bf16x8 a = *(const bf16x8*)(xptr + k);
#pragma unroll
    for (int j = 0; j < NT; ++j) {
      bf16x8 b = *(const bf16x8*)(wptr + (size_t)j * 16 * K + k);
      acc[j] = __builtin_amdgcn_mfma_f32_16x16x32_bf16(a, b, acc[j], 0, 0, 0);
    }
  }
#pragma unroll
  for (int j = 0; j < NT; ++j) {
    int col = j * 16 + l16;
    float bv = bias ? bias[col] : 0.f;
#pragma unroll
    for (int r = 0; r < 4; ++r) {
      int row = mbase + quad * 4 + r;
      float v = acc[j][r] + bv;
      if (out32) out32[(size_t)row * N + col] = v;
      else       out16[(size_t)row * N + col] = f2bf(v);
    }
  }
}

// ---- transpose: dst[n*K + k] (bf16) = src[k*N + n] (f32) ----
__global__ __launch_bounds__(256) void transpose_k(const float* __restrict__ src,
                                                   u16* __restrict__ dst, int K, int N)
{
  int idx = blockIdx.x * 256 + threadIdx.x;
  if (idx >= K * N) return;
  int k = idx / N, n = idx - k * N;
  dst[(size_t)n * K + k] = f2bf(src[idx]);
}

// ---- wr[k][h] = sum_d W[k][h*64+d] * ar[h][d]  (f32) ----
__global__ __launch_bounds__(256) void build_wr(const float* __restrict__ W,
                                                const float* __restrict__ ar,
                                                float* __restrict__ wr, int K)
{
  int idx = blockIdx.x * 256 + threadIdx.x;
  if (idx >= K * 4) return;
  int k = idx >> 2, h = idx & 3;
  float s = 0.f;
  for (int d = 0; d < 64; ++d)
    s += W[(size_t)k * 256 + h * 64 + d] * ar[h * 64 + d];
  wr[idx] = s;
}

// ---- el/er from fs(bf16): el[n][h] = sum_d fs[n][h*64+d]*al[h][d] ----
__global__ __launch_bounds__(256) void elr_kernel(
    const u16* __restrict__ fs, const float* __restrict__ al, const float* __restrict__ ar,
    float* __restrict__ el, float* __restrict__ er, int N)
{
  int nid = blockIdx.x * 4 + (threadIdx.x >> 6);
  if (nid >= N) return;
  int lane = threadIdx.x & 63, h = lane >> 4;
  ushort4 f4 = *(const ushort4*)(fs + (size_t)nid * 256 + lane * 4);
  float f0 = bf2f(f4.x), f1 = bf2f(f4.y), f2 = bf2f(f4.z), f3 = bf2f(f4.w);
  {
    float4 a4 = *(const float4*)(al + lane * 4);
    float p = f0 * a4.x + f1 * a4.y + f2 * a4.z + f3 * a4.w;
    for (int off = 1; off < 16; off <<= 1) p += __shfl_xor(p, off);
    if ((lane & 15) == 0) el[nid * 4 + h] = p;
  }
  if (ar) {
    float4 a4 = *(const float4*)(ar + lane * 4);
    float p = f0 * a4.x + f1 * a4.y + f2 * a4.z + f3 * a4.w;
    for (int off = 1; off < 16; off <<= 1) p += __shfl_xor(p, off);
    if ((lane & 15) == 0) er[nid * 4 + h] = p;
  }
}

// ---- er[n][h] = sum_k X[n][k](bf16) * wr[k][h] ----
__global__ __launch_bounds__(256) void er_wr_kernel(
    const u16* __restrict__ X, const float* __restrict__ wr,
    float* __restrict__ er, int N, int K)
{
  int nid = blockIdx.x * 4 + (threadIdx.x >> 6);
  if (nid >= N) return;
  int lane = threadIdx.x & 63;
  float a0 = 0.f, a1 = 0.f, a2 = 0.f, a3 = 0.f;
  for (int k = lane; k < K; k += 64) {
    float xv = bf2f(X[(size_t)nid * K + k]);
    const float* w = wr + k * 4;
    a0 += xv * w[0]; a1 += xv * w[1]; a2 += xv * w[2]; a3 += xv * w[3];
  }
  for (int off = 1; off < 64; off <<= 1) {
    a0 += __shfl_xor(a0, off); a1 += __shfl_xor(a1, off);
    a2 += __shfl_xor(a2, off); a3 += __shfl_xor(a3, off);
  }
  if (lane == 0) {
    er[nid * 4 + 0] = a0; er[nid * 4 + 1] = a1;
    er[nid * 4 + 2] = a2; er[nid * 4 + 3] = a3;
  }
}

// ---- CSR build ----
__global__ __launch_bounds__(256) void zero_i32(int* p, int n) {
  int i = blockIdx.x * 256 + threadIdx.x;
  if (i < n) p[i] = 0;
}
__global__ __launch_bounds__(256) void hist_kernel(const int* __restrict__ dst, int E,
                                                   int* __restrict__ deg) {
  int i = blockIdx.x * 256 + threadIdx.x;
  if (i < E) atomicAdd(&deg[dst[i]], 1);
}
__global__ __launch_bounds__(256) void scanA(const int* __restrict__ deg,
                                             int* __restrict__ rowptr,
                                             int* __restrict__ bsums, int N) {
  __shared__ int sm[256];
  int t = threadIdx.x, i = blockIdx.x * 256 + t;
  int v = (i < N) ? deg[i] : 0;
  sm[t] = v; __syncthreads();
  for (int off = 1; off < 256; off <<= 1) {
    int add = (t >= off) ? sm[t - off] : 0;
    __syncthreads();
    sm[t] += add;
    __syncthreads();
  }
  if (i < N) rowptr[i] = sm[t] - v;     // exclusive within block
  if (t == 255) bsums[blockIdx.x] = sm[255];
}
__global__ __launch_bounds__(512) void scanB(int* bsums, int nb) {
  __shared__ int sm[512];
  int t = threadIdx.x;
  int v = (t < nb) ? bsums[t] : 0;
  sm[t] = v; __syncthreads();
  for (int off = 1; off < 512; off <<= 1) {
    int add = (t >= off) ? sm[t - off] : 0;
    __syncthreads();
    sm[t] += add;
    __syncthreads();
  }
  if (t < nb) bsums[t] = sm[t] - v;     // exclusive block offsets
}
__global__ __launch_bounds__(256) void scanC(int* __restrict__ rowptr,
                                             const int* __restrict__ bsums, int N, int E) {
  int i = blockIdx.x * 256 + threadIdx.x;
  if (i < N) rowptr[i] += bsums[blockIdx.x];
  if (blockIdx.x == 0 && threadIdx.x == 0) rowptr[N] = E;
}
__global__ __launch_bounds__(256) void copy_i32(int* __restrict__ d, const int* __restrict__ s, int n) {
  int i = blockIdx.x * 256 + threadIdx.x;
  if (i < n) d[i] = s[i];
}
__global__ __launch_bounds__(256) void fill_kernel(const int* __restrict__ src,
                                                   const int* __restrict__ dst, int E,
                                                   int* __restrict__ cursor,
                                                   int* __restrict__ srcs) {
  int i = blockIdx.x * 256 + threadIdx.x;
  if (i < E) {
    int pos = atomicAdd(&cursor[dst[i]], 1);
    srcs[pos] = src[i];
  }
}

// ---- single-pass softmax-agg for one relation; half-wave per edge ----
// lane covers row elements sl*8 .. sl*8+7 (sl = lane&31); head hh = sl>>3.
// Unnormalized softmax: w = exp(leaky(el+er)); normalize by sum(w) at end.
static __device__ __forceinline__ void softagg2(
    int nid, int sl, int half, int hh,
    const int* __restrict__ rp, const int* __restrict__ srcs,
    const float* __restrict__ el, float ern, const u16* __restrict__ fs,
    float* acc, float& sw)
{
  int s0 = rp[nid], s1 = rp[nid + 1];
  int i = s0 + half;
  for (; i + 2 < s1; i += 4) {          // 2 edges per half-wave, 4 in flight/wave
    int sid0 = srcs[i], sid1 = srcs[i + 2];
    float v0 = el[(size_t)sid0 * 4 + hh] + ern;
    float v1 = el[(size_t)sid1 * 4 + hh] + ern;
    bf16x8 r0 = *(const bf16x8*)(fs + (size_t)sid0 * 256 + sl * 8);
    bf16x8 r1 = *(const bf16x8*)(fs + (size_t)sid1 * 256 + sl * 8);
    v0 = v0 > 0.f ? v0 : 0.2f * v0;
    v1 = v1 > 0.f ? v1 : 0.2f * v1;
    float w0 = __expf(v0), w1 = __expf(v1);
    sw += w0 + w1;
#pragma unroll
    for (int j = 0; j < 8; ++j)
      acc[j] += w0 * bf2f((u16)r0[j]) + w1 * bf2f((u16)r1[j]);
  }
  if (i < s1) {
    int sid0 = srcs[i];
    float v0 = el[(size_t)sid0 * 4 + hh] + ern;
    bf16x8 r0 = *(const bf16x8*)(fs + (size_t)sid0 * 256 + sl * 8);
    v0 = v0 > 0.f ? v0 : 0.2f * v0;
    float w0 = __expf(v0);
    sw += w0;
#pragma unroll
    for (int j = 0; j < 8; ++j)
      acc[j] += w0 * bf2f((u16)r0[j]);
  }
}

// ---- paper-dst: rel cites + rel writes ----
__global__ __launch_bounds__(256) void agg_paper(
    const int* __restrict__ rp0, const int* __restrict__ srcs0,
    const float* __restrict__ el0, const float* __restrict__ er0,
    const u16* __restrict__ fs0,
    const int* __restrict__ rp1, const int* __restrict__ srcs1,
    const float* __restrict__ el1, const float* __restrict__ er1,
    const u16* __restrict__ fs1,
    const float* __restrict__ bias0, const float* __restrict__ bias1,
    u16* __restrict__ out, int Nd, int relu)
{
  int nid = blockIdx.x * 4 + (threadIdx.x >> 6);
  if (nid >= Nd) return;
  int lane = threadIdx.x & 63;
  int half = lane >> 5, sl = lane & 31, hh = sl >> 3;
  float o[8];
  {
    float acc[8] = {0.f, 0.f, 0.f, 0.f, 0.f, 0.f, 0.f, 0.f};
    float sw = 0.f;
    softagg2(nid, sl, half, hh, rp0, srcs0, el0, er0[(size_t)nid * 4 + hh], fs0, acc, sw);
    sw += __shfl_xor(sw, 32);
    float inv = sw > 0.f ? 1.f / sw : 0.f;
#pragma unroll
    for (int j = 0; j < 8; ++j)
      o[j] = (acc[j] + __shfl_xor(acc[j], 32)) * inv;
  }
  {
    float acc[8] = {0.f, 0.f, 0.f, 0.f, 0.f, 0.f, 0.f, 0.f};
    float sw = 0.f;
    softagg2(nid, sl, half, hh, rp1, srcs1, el1, er1[(size_t)nid * 4 + hh], fs1, acc, sw);
    sw += __shfl_xor(sw, 32);
    float inv = sw > 0.f ? 1.f / sw : 0.f;
#pragma unroll
    for (int j = 0; j < 8; ++j)
      o[j] += (acc[j] + __shfl_xor(acc[j], 32)) * inv;
  }
  // store (all shfls above are wave-uniform; only the store is divergent)
  if (half == 0) {
    const float* bp0 = bias0 + sl * 8;
    const float* bp1 = bias1 + sl * 8;
    bf16x8 r;
#pragma unroll
    for (int j = 0; j < 8; ++j) {
      float v = o[j] + bp0[j] + bp1[j];
      if (relu) v = fmaxf(v, 0.f);
      r[j] = (short)f2bf(v);
    }
    *(bf16x8*)(out + (size_t)nid * 256 + sl * 8) = r;
  }
}

// ---- author-dst: rel written ----
__global__ __launch_bounds__(256) void agg_author(
    const int* __restrict__ rp0, const int* __restrict__ srcs0,
    const float* __restrict__ el0, const float* __restrict__ er0,
    const u16* __restrict__ fs0,
    const float* __restrict__ bias0, u16* __restrict__ out, int Nd, int relu)
{
  int nid = blockIdx.x * 4 + (threadIdx.x >> 6);
  if (nid >= Nd) return;
  int lane = threadIdx.x & 63;
  int half = lane >> 5, sl = lane & 31, hh = sl >> 3;
  float acc[8] = {0.f, 0.f, 0.f, 0.f, 0.f, 0.f, 0.f, 0.f};
  float sw = 0.f;
  softagg2(nid, sl, half, hh, rp0, srcs0, el0, er0[(size_t)nid * 4 + hh], fs0, acc, sw);
  sw += __shfl_xor(sw, 32);
  float inv = sw > 0.f ? 1.f / sw : 0.f;
  // combine halves WAVE-UNIFORMLY (divergent shfl was the round-3 bug)
#pragma unroll
  for (int j = 0; j < 8; ++j)
    acc[j] = (acc[j] + __shfl_xor(acc[j], 32)) * inv;
  if (half == 0) {
    const float* bp0 = bias0 + sl * 8;
    bf16x8 r;
#pragma unroll
    for (int j = 0; j < 8; ++j) {
      float v = acc[j] + bp0[j];
      if (relu) v = fmaxf(v, 0.f);
      r[j] = (short)f2bf(v);
    }
    *(bf16x8*)(out + (size_t)nid * 256 + sl * 8) = r;
  }
}

static inline int cdiv(int a, int b) { return (a + b - 1) / b; }

extern "C" void kernel_launch(void* const* d_in, const int* in_sizes, int n_in,
                              void* d_out, int out_size, void* d_ws, size_t ws_size,
                              hipStream_t stream)
{
  const float* xp   = (const float*)d_in[0];
  const float* xa   = (const float*)d_in[1];
  const float* W0   = (const float*)d_in[2];   // [3][128][256]
  const float* al0  = (const float*)d_in[3];   // [3][4][64]
  const float* ar0  = (const float*)d_in[4];
  const float* b0   = (const float*)d_in[5];   // [3][256]
  const float* W1   = (const float*)d_in[6];   // [3][256][256]
  const float* al1  = (const float*)d_in[7];
  const float* ar1  = (const float*)d_in[8];
  const float* b1   = (const float*)d_in[9];
  const float* linw = (const float*)d_in[10];  // [256][192]
  const float* linb = (const float*)d_in[11];  // [192]
  const int* srcC = (const int*)d_in[12];
  const int* dstC = (const int*)d_in[13];
  const int* srcW = (const int*)d_in[14];
  const int* dstW = (const int*)d_in[15];
  const int* srcR = (const int*)d_in[16];
  const int* dstR = (const int*)d_in[17];
  float* out = (float*)d_out;

  const int Np = in_sizes[0] / 128;
  const int Na = in_sizes[1] / 128;
  const int E  = in_sizes[12];

  // workspace carve-up (~260 MB, same footprint as the verified round-2 layout)
  char* base = (char*)d_ws;
  size_t off = 0;
  auto alloc = [&](size_t bytes) -> void* {
    void* r = base + off;
    off += (bytes + 255) & ~(size_t)255;
    return r;
  };
  u16* Wt0  = (u16*)alloc((size_t)3 * 256 * 128 * 2);   // [r][n=256][k=128] bf16
  u16* Wt1  = (u16*)alloc((size_t)3 * 256 * 256 * 2);   // [r][n=256][k=256] bf16
  u16* Wtl  = (u16*)alloc((size_t)192 * 256 * 2);       // [n=192][k=256] bf16
  float* wr01 = (float*)alloc(128 * 4 * 4);
  float* wr02 = (float*)alloc(128 * 4 * 4);
  float* wr11 = (float*)alloc(256 * 4 * 4);
  float* wr12 = (float*)alloc(256 * 4 * 4);
  u16* xpb  = (u16*)alloc((size_t)Np * 128 * 2);
  u16* xab  = (u16*)alloc((size_t)Na * 128 * 2);
  u16* fs0p = (u16*)alloc((size_t)Np * 256 * 2);
  u16* fs1a = (u16*)alloc((size_t)Na * 256 * 2);
  u16* fs2p = (u16*)alloc((size_t)Np * 256 * 2);
  u16* h1p  = (u16*)alloc((size_t)Np * 256 * 2);
  u16* h1a  = (u16*)alloc((size_t)Na * 256 * 2);
  float* el0 = (float*)alloc((size_t)Np * 4 * 4);
  float* er0 = (float*)alloc((size_t)Np * 4 * 4);
  float* el1 = (float*)alloc((size_t)Na * 4 * 4);
  float* er1 = (float*)alloc((size_t)Np * 4 * 4);
  float* el2 = (float*)alloc((size_t)Np * 4 * 4);
  float* er2 = (float*)alloc((size_t)Na * 4 * 4);
  int* rpC  = (int*)alloc((size_t)(Np + 1) * 4);
  int* rpW  = (int*)alloc((size_t)(Np + 1) * 4);
  int* rpR  = (int*)alloc((size_t)(Na + 1) * 4);
  int* srcsC = (int*)alloc((size_t)E * 4);
  int* srcsW = (int*)alloc((size_t)E * 4);
  int* srcsR = (int*)alloc((size_t)E * 4);
  int* deg    = (int*)alloc((size_t)Np * 4);
  int* cursor = (int*)alloc((size_t)Np * 4);
  int* bsums  = (int*)alloc(512 * 4);

  // ---- input conversion + weight prep ----
  cvt_f32_bf16<<<cdiv(Np * 32, 256), 256, 0, stream>>>(xp, xpb, Np * 32);
  cvt_f32_bf16<<<cdiv(Na * 32, 256), 256, 0, stream>>>(xa, xab, Na * 32);
  for (int r = 0; r < 3; ++r)
    transpose_k<<<cdiv(128 * 256, 256), 256, 0, stream>>>(W0 + (size_t)r * 32768,
                                                          Wt0 + (size_t)r * 32768, 128, 256);
  for (int r = 0; r < 3; ++r)
    transpose_k<<<cdiv(256 * 256, 256), 256, 0, stream>>>(W1 + (size_t)r * 65536,
                                                          Wt1 + (size_t)r * 65536, 256, 256);
  transpose_k<<<cdiv(256 * 192, 256), 256, 0, stream>>>(linw, Wtl, 256, 192);
  build_wr<<<cdiv(128 * 4, 256), 256, 0, stream>>>(W0 + 1 * 32768, ar0 + 256, wr01, 128);
  build_wr<<<cdiv(128 * 4, 256), 256, 0, stream>>>(W0 + 2 * 32768, ar0 + 512, wr02, 128);
  build_wr<<<cdiv(256 * 4, 256), 256, 0, stream>>>(W1 + 1 * 65536, ar1 + 256, wr11, 256);
  build_wr<<<cdiv(256 * 4, 256), 256, 0, stream>>>(W1 + 2 * 65536, ar1 + 512, wr12, 256);

  // ---- CSR build (shared by both layers) ----
  auto build_csr = [&](const int* src, const int* dst, int Nd, int* rp, int* srcs) {
    int nb = cdiv(Nd, 256);
    zero_i32<<<nb, 256, 0, stream>>>(deg, Nd);
    hist_kernel<<<cdiv(E, 256), 256, 0, stream>>>(dst, E, deg);
    scanA<<<nb, 256, 0, stream>>>(deg, rp, bsums, Nd);
    scanB<<<1, 512, 0, stream>>>(bsums, nb);
    scanC<<<nb, 256, 0, stream>>>(rp, bsums, Nd, E);
    copy_i32<<<nb, 256, 0, stream>>>(cursor, rp, Nd);
    fill_kernel<<<cdiv(E, 256), 256, 0, stream>>>(src, dst, E, cursor, srcs);
  };
  build_csr(srcC, dstC, Np, rpC, srcsC);
  build_csr(srcW, dstW, Np, rpW, srcsW);
  build_csr(srcR, dstR, Na, rpR, srcsR);

  auto layer = [&](const u16* inP, const u16* inA, const u16* WtL, int K,
                   const float* alL, const float* arL,
                   const float* wr1, const float* wr2, const float* bL,
                   u16* outP, u16* outA, int relu) {
    size_t wsz = (size_t)256 * K;
    if (K == 128) {
      gemm_bf16<128, 16><<<dim3(cdiv(Np, 64)), 256, 0, stream>>>(inP, WtL,            fs0p, nullptr, nullptr, Np);
      gemm_bf16<128, 16><<<dim3(cdiv(Na, 64)), 256, 0, stream>>>(inA, WtL + wsz,      fs1a, nullptr, nullptr, Na);
      gemm_bf16<128, 16><<<dim3(cdiv(Np, 64)), 256, 0, stream>>>(inP, WtL + 2 * wsz,  fs2p, nullptr, nullptr, Np);
    } else {
      gemm_bf16<256, 16><<<dim3(cdiv(Np, 64)), 256, 0, stream>>>(inP, WtL,            fs0p, nullptr, nullptr, Np);
      gemm_bf16<256, 16><<<dim3(cdiv(Na, 64)), 256, 0, stream>>>(inA, WtL + wsz,      fs1a, nullptr, nullptr, Na);
      gemm_bf16<256, 16><<<dim3(cdiv(Np, 64)), 256, 0, stream>>>(inP, WtL + 2 * wsz,  fs2p, nullptr, nullptr, Np);
    }
    elr_kernel<<<cdiv(Np, 4), 256, 0, stream>>>(fs0p, alL,       arL, el0, er0, Np);
    elr_kernel<<<cdiv(Na, 4), 256, 0, stream>>>(fs1a, alL + 256, nullptr, el1, nullptr, Na);
    elr_kernel<<<cdiv(Np, 4), 256, 0, stream>>>(fs2p, alL + 512, nullptr, el2, nullptr, Np);
    er_wr_kernel<<<cdiv(Np, 4), 256, 0, stream>>>(inP, wr1, er1, Np, K);
    er_wr_kernel<<<cdiv(Na, 4), 256, 0, stream>>>(inA, wr2, er2, Na, K);
    agg_paper<<<cdiv(Np, 4), 256, 0, stream>>>(rpC, srcsC, el0, er0, fs0p,
                                               rpW, srcsW, el1, er1, fs1a,
                                               bL, bL + 256, outP, Np, relu);
    agg_author<<<cdiv(Na, 4), 256, 0, stream>>>(rpR, srcsR, el2, er2, fs2p,
                                                bL + 512, outA, Na, relu);
  };

  layer(xpb, xab, Wt0, 128, al0, ar0, wr01, wr02, b0, h1p, h1a, 1);
  layer(h1p, h1a, Wt1, 256, al1, ar1, wr11, wr12, b1, h1p, h1a, 0);

  // ---- final linear ----
  gemm_bf16<256, 12><<<dim3(cdiv(Np, 64)), 256, 0, stream>>>(h1p, Wtl, nullptr, out, linb, Np);
}

// Round 5
// 1244.088 us; speedup vs baseline: 1.4403x; 1.1204x over previous
//
#include <hip/hip_runtime.h>

typedef unsigned short u16;
typedef __attribute__((ext_vector_type(8))) short bf16x8;
typedef __attribute__((ext_vector_type(4))) float f32x4;

static __device__ __forceinline__ float bf2f(u16 u) {
  union { unsigned int i; float f; } v; v.i = ((unsigned int)u) << 16; return v.f;
}
static __device__ __forceinline__ u16 f2bf(float f) {
  union { float f; unsigned int i; } v; v.f = f;
  unsigned int i = v.i;
  return (u16)((i + 0x7FFFu + ((i >> 16) & 1u)) >> 16);
}

// ---- convert f32 -> bf16, vectorized ----
__global__ __launch_bounds__(256) void cvt_f32_bf16(const float* __restrict__ src,
                                                    u16* __restrict__ dst, int n4)
{
  int i = blockIdx.x * 256 + threadIdx.x;
  if (i >= n4) return;
  float4 v = ((const float4*)src)[i];
  ushort4 r;
  r.x = f2bf(v.x); r.y = f2bf(v.y); r.z = f2bf(v.z); r.w = f2bf(v.w);
  ((ushort4*)dst)[i] = r;
}

// ---- register-blocked GEMM: out[M,N] = X[M,K]bf16 @ Wt[N,K]^T ----
// block = 4 waves, tile 64 rows x N cols; wave w covers cols w*NTW*16.
// Each wave: 4 m-frags x NTW n-frags -> 16 MFMAs per 8 loads per k-step.
template<int K, int NTW>
__global__ __launch_bounds__(256) void gemm_rb(
    const u16* __restrict__ X, const u16* __restrict__ Wt,
    u16* __restrict__ out16, float* __restrict__ out32,
    const float* __restrict__ bias, int M)
{
  const int N = NTW * 16 * 4;
  int wave = threadIdx.x >> 6, lane = threadIdx.x & 63;
  int quad = lane >> 4, l16 = lane & 15;
  int mbase = blockIdx.x * 64;
  int nbase = wave * (NTW * 16);
  const u16* aptr[4];
#pragma unroll
  for (int mt = 0; mt < 4; ++mt) {
    int row = mbase + mt * 16 + l16;
    row = row < M ? row : M - 1;          // clamp (tail block): reads valid, stores guarded
    aptr[mt] = X + (size_t)row * K + quad * 8;
  }
  const u16* wptr = Wt + (size_t)(nbase + l16) * K + quad * 8;
  f32x4 acc[4][NTW];
#pragma unroll
  for (int mt = 0; mt < 4; ++mt)
#pragma unroll
    for (int nt = 0; nt < NTW; ++nt) acc[mt][nt] = (f32x4){0.f, 0.f, 0.f, 0.f};
  for (int k = 0; k < K; k += 32) {
    bf16x8 a[4], b[NTW];
#pragma unroll
    for (int mt = 0; mt < 4; ++mt) a[mt] = *(const bf16x8*)(aptr[mt] + k);
#pragma unroll
    for (int nt = 0; nt < NTW; ++nt) b[nt] = *(const bf16x8*)(wptr + (size_t)nt * 16 * K + k);
#pragma unroll
    for (int mt = 0; mt < 4; ++mt)
#pragma unroll
      for (int nt = 0; nt < NTW; ++nt)
        acc[mt][nt] = __builtin_amdgcn_mfma_f32_16x16x32_bf16(a[mt], b[nt], acc[mt][nt], 0, 0, 0);
  }
#pragma unroll
  for (int mt = 0; mt < 4; ++mt)
#pragma unroll
    for (int nt = 0; nt < NTW; ++nt) {
      int col = nbase + nt * 16 + l16;
      float bv = bias ? bias[col] : 0.f;
#pragma unroll
      for (int r = 0; r < 4; ++r) {
        int row = mbase + mt * 16 + quad * 4 + r;
        if (row < M) {
          float v = acc[mt][nt][r] + bv;
          if (out32) out32[(size_t)row * N + col] = v;
          else       out16[(size_t)row * N + col] = f2bf(v);
        }
      }
    }
}

// ---- transpose: dst[n*K + k] (bf16) = src[k*N + n] (f32) ----
__global__ __launch_bounds__(256) void transpose_k(const float* __restrict__ src,
                                                   u16* __restrict__ dst, int K, int N)
{
  int idx = blockIdx.x * 256 + threadIdx.x;
  if (idx >= K * N) return;
  int k = idx / N, n = idx - k * N;
  dst[(size_t)n * K + k] = f2bf(src[idx]);
}

// ---- wr[k][h] = sum_d W[k][h*64+d] * ar[h][d]  (f32) ----
__global__ __launch_bounds__(256) void build_wr(const float* __restrict__ W,
                                                const float* __restrict__ ar,
                                                float* __restrict__ wr, int K)
{
  int idx = blockIdx.x * 256 + threadIdx.x;
  if (idx >= K * 4) return;
  int k = idx >> 2, h = idx & 3;
  float s = 0.f;
  for (int d = 0; d < 64; ++d)
    s += W[(size_t)k * 256 + h * 64 + d] * ar[h * 64 + d];
  wr[idx] = s;
}

// ---- el/er from fs(bf16): el[n][h] = sum_d fs[n][h*64+d]*al[h][d] ----
__global__ __launch_bounds__(256) void elr_kernel(
    const u16* __restrict__ fs, const float* __restrict__ al, const float* __restrict__ ar,
    float* __restrict__ el, float* __restrict__ er, int N)
{
  int nid = blockIdx.x * 4 + (threadIdx.x >> 6);
  if (nid >= N) return;
  int lane = threadIdx.x & 63, h = lane >> 4;
  ushort4 f4 = *(const ushort4*)(fs + (size_t)nid * 256 + lane * 4);
  float f0 = bf2f(f4.x), f1 = bf2f(f4.y), f2 = bf2f(f4.z), f3 = bf2f(f4.w);
  {
    float4 a4 = *(const float4*)(al + lane * 4);
    float p = f0 * a4.x + f1 * a4.y + f2 * a4.z + f3 * a4.w;
    for (int off = 1; off < 16; off <<= 1) p += __shfl_xor(p, off);
    if ((lane & 15) == 0) el[nid * 4 + h] = p;
  }
  if (ar) {
    float4 a4 = *(const float4*)(ar + lane * 4);
    float p = f0 * a4.x + f1 * a4.y + f2 * a4.z + f3 * a4.w;
    for (int off = 1; off < 16; off <<= 1) p += __shfl_xor(p, off);
    if ((lane & 15) == 0) er[nid * 4 + h] = p;
  }
}

// ---- er[n][h] = sum_k X[n][k](bf16) * wr[k][h] ----
__global__ __launch_bounds__(256) void er_wr_kernel(
    const u16* __restrict__ X, const float* __restrict__ wr,
    float* __restrict__ er, int N, int K)
{
  int nid = blockIdx.x * 4 + (threadIdx.x >> 6);
  if (nid >= N) return;
  int lane = threadIdx.x & 63;
  float a0 = 0.f, a1 = 0.f, a2 = 0.f, a3 = 0.f;
  for (int k = lane; k < K; k += 64) {
    float xv = bf2f(X[(size_t)nid * K + k]);
    const float* w = wr + k * 4;
    a0 += xv * w[0]; a1 += xv * w[1]; a2 += xv * w[2]; a3 += xv * w[3];
  }
  for (int off = 1; off < 64; off <<= 1) {
    a0 += __shfl_xor(a0, off); a1 += __shfl_xor(a1, off);
    a2 += __shfl_xor(a2, off); a3 += __shfl_xor(a3, off);
  }
  if (lane == 0) {
    er[nid * 4 + 0] = a0; er[nid * 4 + 1] = a1;
    er[nid * 4 + 2] = a2; er[nid * 4 + 3] = a3;
  }
}

// ---- CSR build ----
__global__ __launch_bounds__(256) void zero_i32(int* p, int n) {
  int i = blockIdx.x * 256 + threadIdx.x;
  if (i < n) p[i] = 0;
}
__global__ __launch_bounds__(256) void hist_kernel(const int* __restrict__ dst, int E,
                                                   int* __restrict__ deg) {
  int i = blockIdx.x * 256 + threadIdx.x;
  if (i < E) atomicAdd(&deg[dst[i]], 1);
}
__global__ __launch_bounds__(256) void scanA(const int* __restrict__ deg,
                                             int* __restrict__ rowptr,
                                             int* __restrict__ bsums, int N) {
  __shared__ int sm[256];
  int t = threadIdx.x, i = blockIdx.x * 256 + t;
  int v = (i < N) ? deg[i] : 0;
  sm[t] = v; __syncthreads();
  for (int off = 1; off < 256; off <<= 1) {
    int add = (t >= off) ? sm[t - off] : 0;
    __syncthreads();
    sm[t] += add;
    __syncthreads();
  }
  if (i < N) rowptr[i] = sm[t] - v;     // exclusive within block
  if (t == 255) bsums[blockIdx.x] = sm[255];
}
__global__ __launch_bounds__(512) void scanB(int* bsums, int nb) {
  __shared__ int sm[512];
  int t = threadIdx.x;
  int v = (t < nb) ? bsums[t] : 0;
  sm[t] = v; __syncthreads();
  for (int off = 1; off < 512; off <<= 1) {
    int add = (t >= off) ? sm[t - off] : 0;
    __syncthreads();
    sm[t] += add;
    __syncthreads();
  }
  if (t < nb) bsums[t] = sm[t] - v;     // exclusive block offsets
}
__global__ __launch_bounds__(256) void scanC(int* __restrict__ rowptr,
                                             const int* __restrict__ bsums, int N, int E) {
  int i = blockIdx.x * 256 + threadIdx.x;
  if (i < N) rowptr[i] += bsums[blockIdx.x];
  if (blockIdx.x == 0 && threadIdx.x == 0) rowptr[N] = E;
}
__global__ __launch_bounds__(256) void copy_i32(int* __restrict__ d, const int* __restrict__ s, int n) {
  int i = blockIdx.x * 256 + threadIdx.x;
  if (i < n) d[i] = s[i];
}
__global__ __launch_bounds__(256) void fill_kernel(const int* __restrict__ src,
                                                   const int* __restrict__ dst, int E,
                                                   int* __restrict__ cursor,
                                                   int* __restrict__ srcs) {
  int i = blockIdx.x * 256 + threadIdx.x;
  if (i < E) {
    int pos = atomicAdd(&cursor[dst[i]], 1);
    srcs[pos] = src[i];
  }
}

// ---- single-pass softmax-agg for one relation; half-wave per edge ----
// lane covers row elements sl*8 .. sl*8+7 (sl = lane&31); head hh = sl>>3.
// Unnormalized softmax: w = exp(leaky(el+er)); normalize by sum(w) at end.
static __device__ __forceinline__ void softagg2(
    int nid, int sl, int half, int hh,
    const int* __restrict__ rp, const int* __restrict__ srcs,
    const float* __restrict__ el, float ern, const u16* __restrict__ fs,
    float* acc, float& sw)
{
  int s0 = rp[nid], s1 = rp[nid + 1];
  int i = s0 + half;
  for (; i + 2 < s1; i += 4) {          // 2 edges per half-wave, 4 in flight/wave
    int sid0 = srcs[i], sid1 = srcs[i + 2];
    float v0 = el[(size_t)sid0 * 4 + hh] + ern;
    float v1 = el[(size_t)sid1 * 4 + hh] + ern;
    bf16x8 r0 = *(const bf16x8*)(fs + (size_t)sid0 * 256 + sl * 8);
    bf16x8 r1 = *(const bf16x8*)(fs + (size_t)sid1 * 256 + sl * 8);
    v0 = v0 > 0.f ? v0 : 0.2f * v0;
    v1 = v1 > 0.f ? v1 : 0.2f * v1;
    float w0 = __expf(v0), w1 = __expf(v1);
    sw += w0 + w1;
#pragma unroll
    for (int j = 0; j < 8; ++j)
      acc[j] += w0 * bf2f((u16)r0[j]) + w1 * bf2f((u16)r1[j]);
  }
  if (i < s1) {
    int sid0 = srcs[i];
    float v0 = el[(size_t)sid0 * 4 + hh] + ern;
    bf16x8 r0 = *(const bf16x8*)(fs + (size_t)sid0 * 256 + sl * 8);
    v0 = v0 > 0.f ? v0 : 0.2f * v0;
    float w0 = __expf(v0);
    sw += w0;
#pragma unroll
    for (int j = 0; j < 8; ++j)
      acc[j] += w0 * bf2f((u16)r0[j]);
  }
}

// ---- paper-dst: rel cites + rel writes ----
__global__ __launch_bounds__(256) void agg_paper(
    const int* __restrict__ rp0, const int* __restrict__ srcs0,
    const float* __restrict__ el0, const float* __restrict__ er0,
    const u16* __restrict__ fs0,
    const int* __restrict__ rp1, const int* __restrict__ srcs1,
    const float* __restrict__ el1, const float* __restrict__ er1,
    const u16* __restrict__ fs1,
    const float* __restrict__ bias0, const float* __restrict__ bias1,
    u16* __restrict__ out, int Nd, int relu)
{
  int nid = blockIdx.x * 4 + (threadIdx.x >> 6);
  if (nid >= Nd) return;
  int lane = threadIdx.x & 63;
  int half = lane >> 5, sl = lane & 31, hh = sl >> 3;
  float o[8];
  {
    float acc[8] = {0.f, 0.f, 0.f, 0.f, 0.f, 0.f, 0.f, 0.f};
    float sw = 0.f;
    softagg2(nid, sl, half, hh, rp0, srcs0, el0, er0[(size_t)nid * 4 + hh], fs0, acc, sw);
    sw += __shfl_xor(sw, 32);
    float inv = sw > 0.f ? 1.f / sw : 0.f;
#pragma unroll
    for (int j = 0; j < 8; ++j)
      o[j] = (acc[j] + __shfl_xor(acc[j], 32)) * inv;
  }
  {
    float acc[8] = {0.f, 0.f, 0.f, 0.f, 0.f, 0.f, 0.f, 0.f};
    float sw = 0.f;
    softagg2(nid, sl, half, hh, rp1, srcs1, el1, er1[(size_t)nid * 4 + hh], fs1, acc, sw);
    sw += __shfl_xor(sw, 32);
    float inv = sw > 0.f ? 1.f / sw : 0.f;
#pragma unroll
    for (int j = 0; j < 8; ++j)
      o[j] += (acc[j] + __shfl_xor(acc[j], 32)) * inv;
  }
  // store (all shfls above are wave-uniform; only the store is divergent)
  if (half == 0) {
    const float* bp0 = bias0 + sl * 8;
    const float* bp1 = bias1 + sl * 8;
    bf16x8 r;
#pragma unroll
    for (int j = 0; j < 8; ++j) {
      float v = o[j] + bp0[j] + bp1[j];
      if (relu) v = fmaxf(v, 0.f);
      r[j] = (short)f2bf(v);
    }
    *(bf16x8*)(out + (size_t)nid * 256 + sl * 8) = r;
  }
}

// ---- author-dst: rel written ----
__global__ __launch_bounds__(256) void agg_author(
    const int* __restrict__ rp0, const int* __restrict__ srcs0,
    const float* __restrict__ el0, const float* __restrict__ er0,
    const u16* __restrict__ fs0,
    const float* __restrict__ bias0, u16* __restrict__ out, int Nd, int relu)
{
  int nid = blockIdx.x * 4 + (threadIdx.x >> 6);
  if (nid >= Nd) return;
  int lane = threadIdx.x & 63;
  int half = lane >> 5, sl = lane & 31, hh = sl >> 3;
  float acc[8] = {0.f, 0.f, 0.f, 0.f, 0.f, 0.f, 0.f, 0.f};
  float sw = 0.f;
  softagg2(nid, sl, half, hh, rp0, srcs0, el0, er0[(size_t)nid * 4 + hh], fs0, acc, sw);
  sw += __shfl_xor(sw, 32);
  float inv = sw > 0.f ? 1.f / sw : 0.f;
  // combine halves WAVE-UNIFORMLY (divergent shfl was the round-3 bug)
#pragma unroll
  for (int j = 0; j < 8; ++j)
    acc[j] = (acc[j] + __shfl_xor(acc[j], 32)) * inv;
  if (half == 0) {
    const float* bp0 = bias0 + sl * 8;
    bf16x8 r;
#pragma unroll
    for (int j = 0; j < 8; ++j) {
      float v = acc[j] + bp0[j];
      if (relu) v = fmaxf(v, 0.f);
      r[j] = (short)f2bf(v);
    }
    *(bf16x8*)(out + (size_t)nid * 256 + sl * 8) = r;
  }
}

static inline int cdiv(int a, int b) { return (a + b - 1) / b; }

extern "C" void kernel_launch(void* const* d_in, const int* in_sizes, int n_in,
                              void* d_out, int out_size, void* d_ws, size_t ws_size,
                              hipStream_t stream)
{
  const float* xp   = (const float*)d_in[0];
  const float* xa   = (const float*)d_in[1];
  const float* W0   = (const float*)d_in[2];   // [3][128][256]
  const float* al0  = (const float*)d_in[3];   // [3][4][64]
  const float* ar0  = (const float*)d_in[4];
  const float* b0   = (const float*)d_in[5];   // [3][256]
  const float* W1   = (const float*)d_in[6];   // [3][256][256]
  const float* al1  = (const float*)d_in[7];
  const float* ar1  = (const float*)d_in[8];
  const float* b1   = (const float*)d_in[9];
  const float* linw = (const float*)d_in[10];  // [256][192]
  const float* linb = (const float*)d_in[11];  // [192]
  const int* srcC = (const int*)d_in[12];
  const int* dstC = (const int*)d_in[13];
  const int* srcW = (const int*)d_in[14];
  const int* dstW = (const int*)d_in[15];
  const int* srcR = (const int*)d_in[16];
  const int* dstR = (const int*)d_in[17];
  float* out = (float*)d_out;

  const int Np = in_sizes[0] / 128;
  const int Na = in_sizes[1] / 128;
  const int E  = in_sizes[12];

  // workspace carve-up (~260 MB, verified-safe footprint)
  char* base = (char*)d_ws;
  size_t off = 0;
  auto alloc = [&](size_t bytes) -> void* {
    void* r = base + off;
    off += (bytes + 255) & ~(size_t)255;
    return r;
  };
  u16* Wt0  = (u16*)alloc((size_t)3 * 256 * 128 * 2);   // [r][n=256][k=128] bf16
  u16* Wt1  = (u16*)alloc((size_t)3 * 256 * 256 * 2);   // [r][n=256][k=256] bf16
  u16* Wtl  = (u16*)alloc((size_t)192 * 256 * 2);       // [n=192][k=256] bf16
  float* wr01 = (float*)alloc(128 * 4 * 4);
  float* wr02 = (float*)alloc(128 * 4 * 4);
  float* wr11 = (float*)alloc(256 * 4 * 4);
  float* wr12 = (float*)alloc(256 * 4 * 4);
  u16* xpb  = (u16*)alloc((size_t)Np * 128 * 2);
  u16* xab  = (u16*)alloc((size_t)Na * 128 * 2);
  u16* fs0p = (u16*)alloc((size_t)Np * 256 * 2);
  u16* fs1a = (u16*)alloc((size_t)Na * 256 * 2);
  u16* fs2p = (u16*)alloc((size_t)Np * 256 * 2);
  u16* h1p  = (u16*)alloc((size_t)Np * 256 * 2);
  u16* h1a  = (u16*)alloc((size_t)Na * 256 * 2);
  float* el0 = (float*)alloc((size_t)Np * 4 * 4);
  float* er0 = (float*)alloc((size_t)Np * 4 * 4);
  float* el1 = (float*)alloc((size_t)Na * 4 * 4);
  float* er1 = (float*)alloc((size_t)Np * 4 * 4);
  float* el2 = (float*)alloc((size_t)Np * 4 * 4);
  float* er2 = (float*)alloc((size_t)Na * 4 * 4);
  int* rpC  = (int*)alloc((size_t)(Np + 1) * 4);
  int* rpW  = (int*)alloc((size_t)(Np + 1) * 4);
  int* rpR  = (int*)alloc((size_t)(Na + 1) * 4);
  int* srcsC = (int*)alloc((size_t)E * 4);
  int* srcsW = (int*)alloc((size_t)E * 4);
  int* srcsR = (int*)alloc((size_t)E * 4);
  int* deg    = (int*)alloc((size_t)Np * 4);
  int* cursor = (int*)alloc((size_t)Np * 4);
  int* bsums  = (int*)alloc(512 * 4);

  // ---- input conversion + weight prep ----
  cvt_f32_bf16<<<cdiv(Np * 32, 256), 256, 0, stream>>>(xp, xpb, Np * 32);
  cvt_f32_bf16<<<cdiv(Na * 32, 256), 256, 0, stream>>>(xa, xab, Na * 32);
  for (int r = 0; r < 3; ++r)
    transpose_k<<<cdiv(128 * 256, 256), 256, 0, stream>>>(W0 + (size_t)r * 32768,
                                                          Wt0 + (size_t)r * 32768, 128, 256);
  for (int r = 0; r < 3; ++r)
    transpose_k<<<cdiv(256 * 256, 256), 256, 0, stream>>>(W1 + (size_t)r * 65536,
                                                          Wt1 + (size_t)r * 65536, 256, 256);
  transpose_k<<<cdiv(256 * 192, 256), 256, 0, stream>>>(linw, Wtl, 256, 192);
  build_wr<<<cdiv(128 * 4, 256), 256, 0, stream>>>(W0 + 1 * 32768, ar0 + 256, wr01, 128);
  build_wr<<<cdiv(128 * 4, 256), 256, 0, stream>>>(W0 + 2 * 32768, ar0 + 512, wr02, 128);
  build_wr<<<cdiv(256 * 4, 256), 256, 0, stream>>>(W1 + 1 * 65536, ar1 + 256, wr11, 256);
  build_wr<<<cdiv(256 * 4, 256), 256, 0, stream>>>(W1 + 2 * 65536, ar1 + 512, wr12, 256);

  // ---- CSR build (shared by both layers) ----
  auto build_csr = [&](const int* src, const int* dst, int Nd, int* rp, int* srcs) {
    int nb = cdiv(Nd, 256);
    zero_i32<<<nb, 256, 0, stream>>>(deg, Nd);
    hist_kernel<<<cdiv(E, 256), 256, 0, stream>>>(dst, E, deg);
    scanA<<<nb, 256, 0, stream>>>(deg, rp, bsums, Nd);
    scanB<<<1, 512, 0, stream>>>(bsums, nb);
    scanC<<<nb, 256, 0, stream>>>(rp, bsums, Nd, E);
    copy_i32<<<nb, 256, 0, stream>>>(cursor, rp, Nd);
    fill_kernel<<<cdiv(E, 256), 256, 0, stream>>>(src, dst, E, cursor, srcs);
  };
  build_csr(srcC, dstC, Np, rpC, srcsC);
  build_csr(srcW, dstW, Np, rpW, srcsW);
  build_csr(srcR, dstR, Na, rpR, srcsR);

  auto layer = [&](const u16* inP, const u16* inA, const u16* WtL, int K,
                   const float* alL, const float* arL,
                   const float* wr1, const float* wr2, const float* bL,
                   u16* outP, u16* outA, int relu) {
    size_t wsz = (size_t)256 * K;
    if (K == 128) {
      gemm_rb<128, 4><<<dim3(cdiv(Np, 64)), 256, 0, stream>>>(inP, WtL,            fs0p, nullptr, nullptr, Np);
      gemm_rb<128, 4><<<dim3(cdiv(Na, 64)), 256, 0, stream>>>(inA, WtL + wsz,      fs1a, nullptr, nullptr, Na);
      gemm_rb<128, 4><<<dim3(cdiv(Np, 64)), 256, 0, stream>>>(inP, WtL + 2 * wsz,  fs2p, nullptr, nullptr, Np);
    } else {
      gemm_rb<256, 4><<<dim3(cdiv(Np, 64)), 256, 0, stream>>>(inP, WtL,            fs0p, nullptr, nullptr, Np);
      gemm_rb<256, 4><<<dim3(cdiv(Na, 64)), 256, 0, stream>>>(inA, WtL + wsz,      fs1a, nullptr, nullptr, Na);
      gemm_rb<256, 4><<<dim3(cdiv(Np, 64)), 256, 0, stream>>>(inP, WtL + 2 * wsz,  fs2p, nullptr, nullptr, Np);
    }
    elr_kernel<<<cdiv(Np, 4), 256, 0, stream>>>(fs0p, alL,       arL, el0, er0, Np);
    elr_kernel<<<cdiv(Na, 4), 256, 0, stream>>>(fs1a, alL + 256, nullptr, el1, nullptr, Na);
    elr_kernel<<<cdiv(Np, 4), 256, 0, stream>>>(fs2p, alL + 512, nullptr, el2, nullptr, Np);
    er_wr_kernel<<<cdiv(Np, 4), 256, 0, stream>>>(inP, wr1, er1, Np, K);
    er_wr_kernel<<<cdiv(Na, 4), 256, 0, stream>>>(inA, wr2, er2, Na, K);
    agg_paper<<<cdiv(Np, 4), 256, 0, stream>>>(rpC, srcsC, el0, er0, fs0p,
                                               rpW, srcsW, el1, er1, fs1a,
                                               bL, bL + 256, outP, Np, relu);
    agg_author<<<cdiv(Na, 4), 256, 0, stream>>>(rpR, srcsR, el2, er2, fs2p,
                                                bL + 512, outA, Na, relu);
  };

  layer(xpb, xab, Wt0, 128, al0, ar0, wr01, wr02, b0, h1p, h1a, 1);
  layer(h1p, h1a, Wt1, 256, al1, ar1, wr11, wr12, b1, h1p, h1a, 0);

  // ---- final linear ----
  gemm_rb<256, 3><<<dim3(cdiv(Np, 64)), 256, 0, stream>>>(h1p, Wtl, nullptr, out, linb, Np);
}

// Round 6
// 1240.298 us; speedup vs baseline: 1.4447x; 1.0031x over previous
//
#include <hip/hip_runtime.h>

typedef unsigned short u16;
typedef __attribute__((ext_vector_type(8))) short bf16x8;
typedef __attribute__((ext_vector_type(4))) float f32x4;

static __device__ __forceinline__ float bf2f(u16 u) {
  union { unsigned int i; float f; } v; v.i = ((unsigned int)u) << 16; return v.f;
}
static __device__ __forceinline__ u16 f2bf(float f) {
  union { float f; unsigned int i; } v; v.f = f;
  unsigned int i = v.i;
  return (u16)((i + 0x7FFFu + ((i >> 16) & 1u)) >> 16);
}

// ---- convert f32 -> bf16 for both inputs in one launch ----
__global__ __launch_bounds__(256) void cvt2(const float* __restrict__ a, const float* __restrict__ b,
                                            u16* __restrict__ da, u16* __restrict__ db,
                                            int n4a, int n4b)
{
  int i = blockIdx.x * 256 + threadIdx.x;
  const float* s; u16* d; int j;
  if (i < n4a) { s = a; d = da; j = i; }
  else { j = i - n4a; if (j >= n4b) return; s = b; d = db; }
  float4 v = ((const float4*)s)[j];
  ushort4 r;
  r.x = f2bf(v.x); r.y = f2bf(v.y); r.z = f2bf(v.z); r.w = f2bf(v.w);
  ((ushort4*)d)[j] = r;
}

// ---- transpose R chunks: dst[r][n*K+k] (bf16) = src[r][k*N+n] (f32) ----
__global__ __launch_bounds__(256) void transpose3(const float* __restrict__ src,
                                                  u16* __restrict__ dst, int R, int K, int N)
{
  int idx = blockIdx.x * 256 + threadIdx.x;
  if (idx >= R * K * N) return;
  int r = idx / (K * N), rem = idx - r * K * N;
  int k = rem / N, n = rem - k * N;
  dst[(size_t)r * N * K + (size_t)n * K + k] = f2bf(src[idx]);
}

// ---- wr for two relations of one layer in one launch ----
__global__ __launch_bounds__(256) void build_wr2(
    const float* __restrict__ Wa, const float* __restrict__ Wb,
    const float* __restrict__ ara, const float* __restrict__ arb,
    float* __restrict__ wra, float* __restrict__ wrb, int K)
{
  int idx = blockIdx.x * 256 + threadIdx.x;
  if (idx >= 2 * K * 4) return;
  int sel = idx / (K * 4), rem = idx - sel * K * 4;
  int k = rem >> 2, h = rem & 3;
  const float* W = sel ? Wb : Wa;
  const float* ar = sel ? arb : ara;
  float s = 0.f;
  for (int d = 0; d < 64; ++d)
    s += W[(size_t)k * 256 + h * 64 + d] * ar[h * 64 + d];
  (sel ? wrb : wra)[rem] = s;
}

// ---- register-blocked GEMM + fused el/er epilogue ----
// block = 4 waves, tile 64 rows x N cols; wave w covers cols w*NTW*16.
// When al4 != null (requires NTW==4, N==256): wave w == head w; computes
// el[row][w] = sum_d acc(row, w*64+d)*al4[w*64+d] via in-register dot + shfl.
template<int K, int NTW>
__global__ __launch_bounds__(256) void gemm_rb(
    const u16* __restrict__ X, const u16* __restrict__ Wt,
    u16* __restrict__ out16, float* __restrict__ out32,
    const float* __restrict__ bias,
    const float* __restrict__ al4, const float* __restrict__ ar4,
    float* __restrict__ el, float* __restrict__ er, int M)
{
  const int N = NTW * 16 * 4;
  int wave = threadIdx.x >> 6, lane = threadIdx.x & 63;
  int quad = lane >> 4, l16 = lane & 15;
  int mbase = blockIdx.x * 64;
  int nbase = wave * (NTW * 16);
  const u16* aptr[4];
#pragma unroll
  for (int mt = 0; mt < 4; ++mt) {
    int row = mbase + mt * 16 + l16;
    row = row < M ? row : M - 1;          // clamp (tail block): reads valid, stores guarded
    aptr[mt] = X + (size_t)row * K + quad * 8;
  }
  const u16* wptr = Wt + (size_t)(nbase + l16) * K + quad * 8;
  f32x4 acc[4][NTW];
#pragma unroll
  for (int mt = 0; mt < 4; ++mt)
#pragma unroll
    for (int nt = 0; nt < NTW; ++nt) acc[mt][nt] = (f32x4){0.f, 0.f, 0.f, 0.f};
  for (int k = 0; k < K; k += 32) {
    bf16x8 a[4], b[NTW];
#pragma unroll
    for (int mt = 0; mt < 4; ++mt) a[mt] = *(const bf16x8*)(aptr[mt] + k);
#pragma unroll
    for (int nt = 0; nt < NTW; ++nt) b[nt] = *(const bf16x8*)(wptr + (size_t)nt * 16 * K + k);
#pragma unroll
    for (int mt = 0; mt < 4; ++mt)
#pragma unroll
      for (int nt = 0; nt < NTW; ++nt)
        acc[mt][nt] = __builtin_amdgcn_mfma_f32_16x16x32_bf16(a[mt], b[nt], acc[mt][nt], 0, 0, 0);
  }
#pragma unroll
  for (int mt = 0; mt < 4; ++mt)
#pragma unroll
    for (int nt = 0; nt < NTW; ++nt) {
      int col = nbase + nt * 16 + l16;
      float bv = bias ? bias[col] : 0.f;
#pragma unroll
      for (int r = 0; r < 4; ++r) {
        int row = mbase + mt * 16 + quad * 4 + r;
        if (row < M) {
          float v = acc[mt][nt][r] + bv;
          if (out32) out32[(size_t)row * N + col] = v;
          else       out16[(size_t)row * N + col] = f2bf(v);
        }
      }
    }
  // fused el/er (all shfls wave-uniform; only stores guarded)
  if (al4 != nullptr) {
    float alv[NTW], arv[NTW];
#pragma unroll
    for (int nt = 0; nt < NTW; ++nt) {
      alv[nt] = al4[wave * 64 + nt * 16 + l16];
      arv[nt] = ar4 ? ar4[wave * 64 + nt * 16 + l16] : 0.f;
    }
#pragma unroll
    for (int mt = 0; mt < 4; ++mt) {
#pragma unroll
      for (int r = 0; r < 4; ++r) {
        float p = 0.f, q = 0.f;
#pragma unroll
        for (int nt = 0; nt < NTW; ++nt) {
          p += acc[mt][nt][r] * alv[nt];
          q += acc[mt][nt][r] * arv[nt];
        }
#pragma unroll
        for (int off = 1; off < 16; off <<= 1) {
          p += __shfl_xor(p, off);
          q += __shfl_xor(q, off);
        }
        int row = mbase + mt * 16 + quad * 4 + r;
        if (l16 == 0 && row < M) {
          el[row * 4 + wave] = p;
          if (ar4) er[row * 4 + wave] = q;
        }
      }
    }
  }
}

// ---- er[n][h] = sum_k X[n][k](bf16) * wr[k][h]; paper + author in one launch ----
__global__ __launch_bounds__(256) void er_wr2(
    const u16* __restrict__ Xp, const u16* __restrict__ Xa,
    const float* __restrict__ wrp, const float* __restrict__ wra,
    float* __restrict__ erp, float* __restrict__ era, int Np, int Na, int K)
{
  int nblkP = (Np + 3) / 4;
  int bid = blockIdx.x;
  const u16* X; const float* wr; float* er; int nid, Nn;
  if (bid < nblkP) { X = Xp; wr = wrp; er = erp; Nn = Np; nid = bid * 4 + (threadIdx.x >> 6); }
  else { X = Xa; wr = wra; er = era; Nn = Na; nid = (bid - nblkP) * 4 + (threadIdx.x >> 6); }
  if (nid >= Nn) return;
  int lane = threadIdx.x & 63;
  float a0 = 0.f, a1 = 0.f, a2 = 0.f, a3 = 0.f;
  for (int k = lane; k < K; k += 64) {
    float xv = bf2f(X[(size_t)nid * K + k]);
    const float* w = wr + k * 4;
    a0 += xv * w[0]; a1 += xv * w[1]; a2 += xv * w[2]; a3 += xv * w[3];
  }
  for (int off = 1; off < 64; off <<= 1) {
    a0 += __shfl_xor(a0, off); a1 += __shfl_xor(a1, off);
    a2 += __shfl_xor(a2, off); a3 += __shfl_xor(a3, off);
  }
  if (lane == 0) {
    er[nid * 4 + 0] = a0; er[nid * 4 + 1] = a1;
    er[nid * 4 + 2] = a2; er[nid * 4 + 3] = a3;
  }
}

// ---- merged CSR build for 3 relations (C: Np dsts, W: Np dsts, R: Na dsts) ----
__global__ __launch_bounds__(256) void zero3(int* p, int n) {
  int i = blockIdx.x * 256 + threadIdx.x;
  if (i < n) p[i] = 0;
}
__global__ __launch_bounds__(256) void hist3(
    const int* __restrict__ dC, const int* __restrict__ dW, const int* __restrict__ dR,
    int E, int Np, int* __restrict__ deg3)
{
  int i = blockIdx.x * 256 + threadIdx.x;
  if (i >= 3 * E) return;
  int rel = i / E, e = i - rel * E;
  int d, base;
  if (rel == 0) { d = dC[e]; base = 0; }
  else if (rel == 1) { d = dW[e]; base = Np; }
  else { d = dR[e]; base = 2 * Np; }
  atomicAdd(&deg3[base + d], 1);
}
__global__ __launch_bounds__(256) void scanA3(
    const int* __restrict__ deg3, int* __restrict__ rpC, int* __restrict__ rpW,
    int* __restrict__ rpR, int* __restrict__ bsums, int Np, int Na, int nbC)
{
  __shared__ int sm[256];
  int b = blockIdx.x, t = threadIdx.x;
  int lb, Nrel, base; int* rp;
  if (b < nbC) { lb = b; Nrel = Np; base = 0; rp = rpC; }
  else if (b < 2 * nbC) { lb = b - nbC; Nrel = Np; base = Np; rp = rpW; }
  else { lb = b - 2 * nbC; Nrel = Na; base = 2 * Np; rp = rpR; }
  int i = lb * 256 + t;
  int v = (i < Nrel) ? deg3[base + i] : 0;
  sm[t] = v; __syncthreads();
  for (int off = 1; off < 256; off <<= 1) {
    int add = (t >= off) ? sm[t - off] : 0;
    __syncthreads();
    sm[t] += add;
    __syncthreads();
  }
  if (i < Nrel) rp[i] = sm[t] - v;      // exclusive within block
  if (t == 255) bsums[b] = sm[255];
}
__global__ __launch_bounds__(1024) void scanB1024(int* bsums, int nb) {
  __shared__ int sm[1024];
  int t = threadIdx.x;
  int v = (t < nb) ? bsums[t] : 0;
  sm[t] = v; __syncthreads();
  for (int off = 1; off < 1024; off <<= 1) {
    int add = (t >= off) ? sm[t - off] : 0;
    __syncthreads();
    sm[t] += add;
    __syncthreads();
  }
  if (t < nb) bsums[t] = sm[t] - v;     // exclusive block offsets (global)
}
__global__ __launch_bounds__(256) void scanC3(
    int* __restrict__ rpC, int* __restrict__ rpW, int* __restrict__ rpR,
    const int* __restrict__ bsums, int* __restrict__ cursor3,
    int Np, int Na, int nbC, int E)
{
  int b = blockIdx.x, t = threadIdx.x;
  int lb, Nrel, base, rel; int* rp;
  if (b < nbC) { rel = 0; lb = b; Nrel = Np; base = 0; rp = rpC; }
  else if (b < 2 * nbC) { rel = 1; lb = b - nbC; Nrel = Np; base = Np; rp = rpW; }
  else { rel = 2; lb = b - 2 * nbC; Nrel = Na; base = 2 * Np; rp = rpR; }
  int i = lb * 256 + t;
  int add = bsums[b] - rel * E;         // global scan includes previous relations' E each
  if (i < Nrel) {
    int v = rp[i] + add;
    rp[i] = v;
    cursor3[base + i] = v;
  }
  if (lb == 0 && t == 0) rp[Nrel] = E;
}
__global__ __launch_bounds__(256) void fill3(
    const int* __restrict__ sC, const int* __restrict__ dC,
    const int* __restrict__ sW, const int* __restrict__ dW,
    const int* __restrict__ sR, const int* __restrict__ dR,
    int E, int Np, int* __restrict__ cursor3,
    int* __restrict__ oC, int* __restrict__ oW, int* __restrict__ oR)
{
  int i = blockIdx.x * 256 + threadIdx.x;
  if (i >= 3 * E) return;
  int rel = i / E, e = i - rel * E;
  const int *s, *d; int base; int* o;
  if (rel == 0) { s = sC; d = dC; base = 0; o = oC; }
  else if (rel == 1) { s = sW; d = dW; base = Np; o = oW; }
  else { s = sR; d = dR; base = 2 * Np; o = oR; }
  int pos = atomicAdd(&cursor3[base + d[e]], 1);
  o[pos] = s[e];
}

// ---- single-pass softmax-agg; half-wave per edge; packed f32 accumulate ----
static __device__ __forceinline__ void pk2(float2& a, unsigned int u, float w) {
  union { unsigned int i; float f; } lo, hi;
  lo.i = u << 16; hi.i = u & 0xffff0000u;
  a.x += w * lo.f;
  a.y += w * hi.f;
}
static __device__ __forceinline__ void softagg2(
    int nid, int sl, int half, int hh,
    const int* __restrict__ rp, const int* __restrict__ srcs,
    const float* __restrict__ el, float ern, const u16* __restrict__ fs,
    float2* acc2, float& sw)
{
  int s0 = rp[nid], s1 = rp[nid + 1];
  int i = s0 + half;
  for (; i + 2 < s1; i += 4) {          // 2 edges per half-wave, 4 rows in flight/wave
    int sid0 = srcs[i], sid1 = srcs[i + 2];
    float v0 = el[(size_t)sid0 * 4 + hh] + ern;
    float v1 = el[(size_t)sid1 * 4 + hh] + ern;
    uint4 r0 = *(const uint4*)(fs + (size_t)sid0 * 256 + sl * 8);
    uint4 r1 = *(const uint4*)(fs + (size_t)sid1 * 256 + sl * 8);
    v0 = v0 > 0.f ? v0 : 0.2f * v0;
    v1 = v1 > 0.f ? v1 : 0.2f * v1;
    float w0 = __expf(v0), w1 = __expf(v1);
    sw += w0 + w1;
    pk2(acc2[0], r0.x, w0); pk2(acc2[1], r0.y, w0);
    pk2(acc2[2], r0.z, w0); pk2(acc2[3], r0.w, w0);
    pk2(acc2[0], r1.x, w1); pk2(acc2[1], r1.y, w1);
    pk2(acc2[2], r1.z, w1); pk2(acc2[3], r1.w, w1);
  }
  if (i < s1) {
    int sid0 = srcs[i];
    float v0 = el[(size_t)sid0 * 4 + hh] + ern;
    uint4 r0 = *(const uint4*)(fs + (size_t)sid0 * 256 + sl * 8);
    v0 = v0 > 0.f ? v0 : 0.2f * v0;
    float w0 = __expf(v0);
    sw += w0;
    pk2(acc2[0], r0.x, w0); pk2(acc2[1], r0.y, w0);
    pk2(acc2[2], r0.z, w0); pk2(acc2[3], r0.w, w0);
  }
}

// ---- paper-dst: rel cites + rel writes ----
__global__ __launch_bounds__(256) void agg_paper(
    const int* __restrict__ rp0, const int* __restrict__ srcs0,
    const float* __restrict__ el0, const float* __restrict__ er0,
    const u16* __restrict__ fs0,
    const int* __restrict__ rp1, const int* __restrict__ srcs1,
    const float* __restrict__ el1, const float* __restrict__ er1,
    const u16* __restrict__ fs1,
    const float* __restrict__ bias0, const float* __restrict__ bias1,
    u16* __restrict__ out, int Nd, int relu)
{
  int nid = blockIdx.x * 4 + (threadIdx.x >> 6);
  if (nid >= Nd) return;
  int lane = threadIdx.x & 63;
  int half = lane >> 5, sl = lane & 31, hh = sl >> 3;
  float o[8];
  {
    float2 acc2[4] = {{0.f,0.f},{0.f,0.f},{0.f,0.f},{0.f,0.f}};
    float sw = 0.f;
    softagg2(nid, sl, half, hh, rp0, srcs0, el0, er0[(size_t)nid * 4 + hh], fs0, acc2, sw);
    sw += __shfl_xor(sw, 32);
    float inv = sw > 0.f ? 1.f / sw : 0.f;
#pragma unroll
    for (int k = 0; k < 4; ++k) {
      o[2 * k]     = (acc2[k].x + __shfl_xor(acc2[k].x, 32)) * inv;
      o[2 * k + 1] = (acc2[k].y + __shfl_xor(acc2[k].y, 32)) * inv;
    }
  }
  {
    float2 acc2[4] = {{0.f,0.f},{0.f,0.f},{0.f,0.f},{0.f,0.f}};
    float sw = 0.f;
    softagg2(nid, sl, half, hh, rp1, srcs1, el1, er1[(size_t)nid * 4 + hh], fs1, acc2, sw);
    sw += __shfl_xor(sw, 32);
    float inv = sw > 0.f ? 1.f / sw : 0.f;
#pragma unroll
    for (int k = 0; k < 4; ++k) {
      o[2 * k]     += (acc2[k].x + __shfl_xor(acc2[k].x, 32)) * inv;
      o[2 * k + 1] += (acc2[k].y + __shfl_xor(acc2[k].y, 32)) * inv;
    }
  }
  if (half == 0) {
    const float* bp0 = bias0 + sl * 8;
    const float* bp1 = bias1 + sl * 8;
    bf16x8 r;
#pragma unroll
    for (int j = 0; j < 8; ++j) {
      float v = o[j] + bp0[j] + bp1[j];
      if (relu) v = fmaxf(v, 0.f);
      r[j] = (short)f2bf(v);
    }
    *(bf16x8*)(out + (size_t)nid * 256 + sl * 8) = r;
  }
}

// ---- author-dst: rel written ----
__global__ __launch_bounds__(256) void agg_author(
    const int* __restrict__ rp0, const int* __restrict__ srcs0,
    const float* __restrict__ el0, const float* __restrict__ er0,
    const u16* __restrict__ fs0,
    const float* __restrict__ bias0, u16* __restrict__ out, int Nd, int relu)
{
  int nid = blockIdx.x * 4 + (threadIdx.x >> 6);
  if (nid >= Nd) return;
  int lane = threadIdx.x & 63;
  int half = lane >> 5, sl = lane & 31, hh = sl >> 3;
  float2 acc2[4] = {{0.f,0.f},{0.f,0.f},{0.f,0.f},{0.f,0.f}};
  float sw = 0.f;
  softagg2(nid, sl, half, hh, rp0, srcs0, el0, er0[(size_t)nid * 4 + hh], fs0, acc2, sw);
  sw += __shfl_xor(sw, 32);
  float inv = sw > 0.f ? 1.f / sw : 0.f;
  float o[8];
#pragma unroll
  for (int k = 0; k < 4; ++k) {
    o[2 * k]     = (acc2[k].x + __shfl_xor(acc2[k].x, 32)) * inv;
    o[2 * k + 1] = (acc2[k].y + __shfl_xor(acc2[k].y, 32)) * inv;
  }
  if (half == 0) {
    const float* bp0 = bias0 + sl * 8;
    bf16x8 r;
#pragma unroll
    for (int j = 0; j < 8; ++j) {
      float v = o[j] + bp0[j];
      if (relu) v = fmaxf(v, 0.f);
      r[j] = (short)f2bf(v);
    }
    *(bf16x8*)(out + (size_t)nid * 256 + sl * 8) = r;
  }
}

static inline int cdiv(int a, int b) { return (a + b - 1) / b; }

extern "C" void kernel_launch(void* const* d_in, const int* in_sizes, int n_in,
                              void* d_out, int out_size, void* d_ws, size_t ws_size,
                              hipStream_t stream)
{
  const float* xp   = (const float*)d_in[0];
  const float* xa   = (const float*)d_in[1];
  const float* W0   = (const float*)d_in[2];   // [3][128][256]
  const float* al0  = (const float*)d_in[3];   // [3][4][64]
  const float* ar0  = (const float*)d_in[4];
  const float* b0   = (const float*)d_in[5];   // [3][256]
  const float* W1   = (const float*)d_in[6];   // [3][256][256]
  const float* al1  = (const float*)d_in[7];
  const float* ar1  = (const float*)d_in[8];
  const float* b1   = (const float*)d_in[9];
  const float* linw = (const float*)d_in[10];  // [256][192]
  const float* linb = (const float*)d_in[11];  // [192]
  const int* srcC = (const int*)d_in[12];
  const int* dstC = (const int*)d_in[13];
  const int* srcW = (const int*)d_in[14];
  const int* dstW = (const int*)d_in[15];
  const int* srcR = (const int*)d_in[16];
  const int* dstR = (const int*)d_in[17];
  float* out = (float*)d_out;

  const int Np = in_sizes[0] / 128;
  const int Na = in_sizes[1] / 128;
  const int E  = in_sizes[12];

  // workspace carve-up (~265 MB; round-3 ran with ~292 MB so this is safe)
  char* base = (char*)d_ws;
  size_t off = 0;
  auto alloc = [&](size_t bytes) -> void* {
    void* r = base + off;
    off += (bytes + 255) & ~(size_t)255;
    return r;
  };
  u16* Wt0  = (u16*)alloc((size_t)3 * 256 * 128 * 2);   // [r][n=256][k=128] bf16
  u16* Wt1  = (u16*)alloc((size_t)3 * 256 * 256 * 2);   // [r][n=256][k=256] bf16
  u16* Wtl  = (u16*)alloc((size_t)192 * 256 * 2);       // [n=192][k=256] bf16
  float* wr01 = (float*)alloc(128 * 4 * 4);
  float* wr02 = (float*)alloc(128 * 4 * 4);
  float* wr11 = (float*)alloc(256 * 4 * 4);
  float* wr12 = (float*)alloc(256 * 4 * 4);
  u16* xpb  = (u16*)alloc((size_t)Np * 128 * 2);
  u16* xab  = (u16*)alloc((size_t)Na * 128 * 2);
  u16* fs0p = (u16*)alloc((size_t)Np * 256 * 2);
  u16* fs1a = (u16*)alloc((size_t)Na * 256 * 2);
  u16* fs2p = (u16*)alloc((size_t)Np * 256 * 2);
  u16* h1p  = (u16*)alloc((size_t)Np * 256 * 2);
  u16* h1a  = (u16*)alloc((size_t)Na * 256 * 2);
  float* el0 = (float*)alloc((size_t)Np * 4 * 4);
  float* er0 = (float*)alloc((size_t)Np * 4 * 4);
  float* el1 = (float*)alloc((size_t)Na * 4 * 4);
  float* er1 = (float*)alloc((size_t)Np * 4 * 4);
  float* el2 = (float*)alloc((size_t)Np * 4 * 4);
  float* er2 = (float*)alloc((size_t)Na * 4 * 4);
  int* rpC  = (int*)alloc((size_t)(Np + 1) * 4);
  int* rpW  = (int*)alloc((size_t)(Np + 1) * 4);
  int* rpR  = (int*)alloc((size_t)(Na + 1) * 4);
  int* srcsC = (int*)alloc((size_t)E * 4);
  int* srcsW = (int*)alloc((size_t)E * 4);
  int* srcsR = (int*)alloc((size_t)E * 4);
  int* deg3    = (int*)alloc((size_t)(2 * Np + Na) * 4);  // doubles as cursor source
  int* cursor3 = (int*)alloc((size_t)(2 * Np + Na) * 4);
  int* bsums   = (int*)alloc(1024 * 4);

  // ---- input conversion + weight prep ----
  cvt2<<<cdiv(Np * 32 + Na * 32, 256), 256, 0, stream>>>(xp, xa, xpb, xab, Np * 32, Na * 32);
  transpose3<<<cdiv(3 * 128 * 256, 256), 256, 0, stream>>>(W0, Wt0, 3, 128, 256);
  transpose3<<<cdiv(3 * 256 * 256, 256), 256, 0, stream>>>(W1, Wt1, 3, 256, 256);
  transpose3<<<cdiv(256 * 192, 256), 256, 0, stream>>>(linw, Wtl, 1, 256, 192);
  build_wr2<<<cdiv(2 * 128 * 4, 256), 256, 0, stream>>>(W0 + 32768, W0 + 65536,
                                                        ar0 + 256, ar0 + 512, wr01, wr02, 128);
  build_wr2<<<cdiv(2 * 256 * 4, 256), 256, 0, stream>>>(W1 + 65536, W1 + 131072,
                                                        ar1 + 256, ar1 + 512, wr11, wr12, 256);

  // ---- merged CSR build ----
  const int nbC = cdiv(Np, 256), nbR = cdiv(Na, 256);
  const int nb3 = 2 * nbC + nbR;
  zero3<<<cdiv(2 * Np + Na, 256), 256, 0, stream>>>(deg3, 2 * Np + Na);
  hist3<<<cdiv(3 * E, 256), 256, 0, stream>>>(dstC, dstW, dstR, E, Np, deg3);
  scanA3<<<nb3, 256, 0, stream>>>(deg3, rpC, rpW, rpR, bsums, Np, Na, nbC);
  scanB1024<<<1, 1024, 0, stream>>>(bsums, nb3);
  scanC3<<<nb3, 256, 0, stream>>>(rpC, rpW, rpR, bsums, cursor3, Np, Na, nbC, E);
  fill3<<<cdiv(3 * E, 256), 256, 0, stream>>>(srcC, dstC, srcW, dstW, srcR, dstR,
                                              E, Np, cursor3, srcsC, srcsW, srcsR);

  auto layer = [&](const u16* inP, const u16* inA, const u16* WtL, int K,
                   const float* alL, const float* arL,
                   const float* wr1, const float* wr2, const float* bL,
                   u16* outP, u16* outA, int relu) {
    size_t wsz = (size_t)256 * K;
    if (K == 128) {
      gemm_rb<128, 4><<<dim3(cdiv(Np, 64)), 256, 0, stream>>>(
          inP, WtL, fs0p, nullptr, nullptr, alL, arL, el0, er0, Np);
      gemm_rb<128, 4><<<dim3(cdiv(Na, 64)), 256, 0, stream>>>(
          inA, WtL + wsz, fs1a, nullptr, nullptr, alL + 256, nullptr, el1, nullptr, Na);
      gemm_rb<128, 4><<<dim3(cdiv(Np, 64)), 256, 0, stream>>>(
          inP, WtL + 2 * wsz, fs2p, nullptr, nullptr, alL + 512, nullptr, el2, nullptr, Np);
    } else {
      gemm_rb<256, 4><<<dim3(cdiv(Np, 64)), 256, 0, stream>>>(
          inP, WtL, fs0p, nullptr, nullptr, alL, arL, el0, er0, Np);
      gemm_rb<256, 4><<<dim3(cdiv(Na, 64)), 256, 0, stream>>>(
          inA, WtL + wsz, fs1a, nullptr, nullptr, alL + 256, nullptr, el1, nullptr, Na);
      gemm_rb<256, 4><<<dim3(cdiv(Np, 64)), 256, 0, stream>>>(
          inP, WtL + 2 * wsz, fs2p, nullptr, nullptr, alL + 512, nullptr, el2, nullptr, Np);
    }
    er_wr2<<<cdiv(Np, 4) + cdiv(Na, 4), 256, 0, stream>>>(inP, inA, wr1, wr2, er1, er2, Np, Na, K);
    agg_paper<<<cdiv(Np, 4), 256, 0, stream>>>(rpC, srcsC, el0, er0, fs0p,
                                               rpW, srcsW, el1, er1, fs1a,
                                               bL, bL + 256, outP, Np, relu);
    agg_author<<<cdiv(Na, 4), 256, 0, stream>>>(rpR, srcsR, el2, er2, fs2p,
                                                bL + 512, outA, Na, relu);
  };

  layer(xpb, xab, Wt0, 128, al0, ar0, wr01, wr02, b0, h1p, h1a, 1);
  layer(h1p, h1a, Wt1, 256, al1, ar1, wr11, wr12, b1, h1p, h1a, 0);

  // ---- final linear ----
  gemm_rb<256, 3><<<dim3(cdiv(Np, 64)), 256, 0, stream>>>(
      h1p, Wtl, nullptr, out, linb, nullptr, nullptr, nullptr, nullptr, Np);
}